// Round 4
// baseline (1917.971 us; speedup 1.0000x reference)
//
#include <hip/hip_runtime.h>
#include <hip/hip_bf16.h>

#define T_   20
#define B_   4
#define NN_  500
#define M_   2000
#define TM_  40000   // T_*M_
#define H_   128
#define G_   512     // 4*H_
#define H2_  64
#define OUT_ 32
#define ECAP 64
#define TG_  (T_ * G_)

typedef unsigned short ushort_t;
typedef unsigned int   uint_t;
typedef _Float16       f16;
typedef f16 f16x2 __attribute__((ext_vector_type(2)));
typedef f16 f16x8 __attribute__((ext_vector_type(8)));
typedef float f32x4 __attribute__((ext_vector_type(4)));

#if defined(__has_builtin)
#  if __has_builtin(__builtin_amdgcn_fdot2)
#    define HAVE_FDOT2 1
#  endif
#endif

__device__ inline float fdot2_(f16x2 a, f16x2 b, float c) {
#ifdef HAVE_FDOT2
    return __builtin_amdgcn_fdot2(a, b, c, false);
#else
    return c + (float)a.x * (float)b.x + (float)a.y * (float)b.y;
#endif
}

__device__ inline float fast_sig(float x) {
    float e = __builtin_amdgcn_exp2f(x * -1.4426950408889634f);
    return __builtin_amdgcn_rcpf(1.f + e);
}
__device__ inline float fast_tanh(float x) {
    float e = __builtin_amdgcn_exp2f(x * 2.8853900817779268f);
    return 1.f - 2.f * __builtin_amdgcn_rcpf(e + 1.f);
}

// raw barrier: no compiler-inserted s_waitcnt vmcnt(0) drain.
// LDS pipe is in-order per CU: ds ops issued before the barrier land
// before ds ops issued after it (validated R3: correct results).
#define BARRAW() asm volatile("s_barrier" ::: "memory")

// ---- K0: detect ego dtype + build mask[t][i] + zero ecnt ---------------
__global__ __launch_bounds__(1024) void k0_mask(const void* __restrict__ ego,
                                                float* __restrict__ mf,
                                                int* __restrict__ ecnt) {
    __shared__ int fl[3];
    int tid = threadIdx.x;
    if (tid < 3) fl[tid] = 0;
    __syncthreads();
    const uint_t* dw = (const uint_t*)ego;
    int a = 0, b = 0, c = 0;
    for (int i = tid; i < 2500; i += 1024) {   // 10 KB <= any dtype's size
        uint_t v = dw[i];
        bool isf32  = (v == 0x3F800000u);
        bool isbf16 = (v == 0x00003F80u) || (v == 0x3F803F80u);
        if (isf32)  a = 1;
        if (isbf16) b = 1;
        if (v > 1u && !isf32 && !isbf16) c = 1;
    }
    if (a) fl[0] = 1;
    if (b) fl[1] = 1;
    if (c) fl[2] = 1;
    __syncthreads();
    int mode;                       // 0=int32, 1=uint8, 2=f32, 3=bf16
    if (fl[1])      mode = 3;
    else if (fl[0]) mode = 2;
    else if (fl[2]) mode = 1;
    else            mode = 0;
    int e = blockIdx.x * 1024 + tid;
    if (e >= TM_) return;
    ecnt[e] = 0;
    int t = e / M_, i = e % M_;
    int bb = i / NN_, n = i % NN_;
    int src = (bb * T_ + t) * NN_ + n;
    bool on;
    if (mode == 0)      on = ((const int*)ego)[src] != 0;
    else if (mode == 1) on = ((const unsigned char*)ego)[src] != 0;
    else if (mode == 2) on = ((const float*)ego)[src] != 0.f;
    else                on = ((const ushort_t*)ego)[src] != 0;
    mf[e] = on ? 1.f : 0.f;
}

// ---- K1: strip-parallel adjacency scan, atomic slot alloc --------------
#define JSTRIP 200
__global__ void k1_scan(const float* __restrict__ adj, const float* __restrict__ mf,
                        int* __restrict__ ecnt, int* __restrict__ edges) {
    __shared__ float ms[JSTRIP];
    int t = blockIdx.y, j0 = blockIdx.z * JSTRIP;
    int i = blockIdx.x * 256 + threadIdx.x;
    for (int idx = threadIdx.x; idx < JSTRIP; idx += 256)
        ms[idx] = mf[t * M_ + j0 + idx];
    __syncthreads();
    if (i >= M_) return;
    if (mf[t * M_ + i] == 0.f) return;          // masked column: no edges
    const float* ap = adj + (size_t)t * M_ * M_ + (size_t)j0 * M_ + i;
    int r = t * M_ + i;
    int* ep = edges + (size_t)r * ECAP;
#pragma unroll 8
    for (int jj = 0; jj < JSTRIP; ++jj) {
        float av = ap[(size_t)jj * M_];
        if (av != 0.f && ms[jj] != 0.f) {
            int pos = atomicAdd(&ecnt[r], 1);
            if (pos < ECAP) ep[pos] = j0 + jj;
        }
    }
}

// ---- K2: dinv from ecnt/mf; Y1 = dinv * (x @ W1) -----------------------
__global__ void k2_y1(const float* __restrict__ pos, const float* __restrict__ W1,
                      const float* __restrict__ mf, const int* __restrict__ ecnt,
                      float* __restrict__ dinv, f16* __restrict__ Y1) {
    int gid = blockIdx.x * 256 + threadIdx.x;    // over TM_*H_
    int r = gid >> 7, h = gid & 127;
    if (r >= TM_) return;
    float mr = mf[r];
    int cnt = ecnt[r];
    float dv = (mr != 0.f) ? __frsqrt_rn((float)(cnt + 1)) : 0.f;
    if (h == 0) dinv[r] = dv;
    float2 xy = ((const float2*)pos)[r];
    float v = xy.x * W1[h] + xy.y * W1[H_ + h];
    Y1[gid] = (f16)(dv * v);
}

// ---- K3: h1 = relu(dinv*(sum_edges Y1 + Y1_self) + b1), f16x2 lanes ----
__global__ __launch_bounds__(64) void k3_agg1(const f16* __restrict__ Y1,
        const float* __restrict__ dinv, const int* __restrict__ ecnt,
        const int* __restrict__ edges, const float* __restrict__ b1,
        f16* __restrict__ h1) {
    int r = blockIdx.x, q = threadIdx.x;   // q: h-pair index 0..63
    int t = r / M_, base = t * M_;
    const uint_t* Yu = (const uint_t*)Y1;
    f16x2 sp = __builtin_bit_cast(f16x2, Yu[(size_t)r * 64 + q]);
    float a0 = (float)sp.x, a1 = (float)sp.y;
    int ec = ecnt[r]; if (ec > ECAP) ec = ECAP;
    const int4* ep4 = (const int4*)(edges + (size_t)r * ECAP);
    for (int e = 0; e < ec; e += 4) {
        int4 ix = ep4[e >> 2];
        int j1 = (e + 1 < ec) ? ix.y : ix.x;
        int j2 = (e + 2 < ec) ? ix.z : ix.x;
        int j3 = (e + 3 < ec) ? ix.w : ix.x;
        uint_t u0 = Yu[(size_t)(base + ix.x) * 64 + q];
        uint_t u1 = Yu[(size_t)(base + j1) * 64 + q];
        uint_t u2 = Yu[(size_t)(base + j2) * 64 + q];
        uint_t u3 = Yu[(size_t)(base + j3) * 64 + q];
        f16x2 p0 = __builtin_bit_cast(f16x2, u0);
        a0 += (float)p0.x; a1 += (float)p0.y;
        if (e + 1 < ec) { f16x2 p = __builtin_bit_cast(f16x2, u1); a0 += (float)p.x; a1 += (float)p.y; }
        if (e + 2 < ec) { f16x2 p = __builtin_bit_cast(f16x2, u2); a0 += (float)p.x; a1 += (float)p.y; }
        if (e + 3 < ec) { f16x2 p = __builtin_bit_cast(f16x2, u3); a0 += (float)p.x; a1 += (float)p.y; }
    }
    float dv = dinv[r];
    float o0 = dv * a0 + b1[2 * q];
    float o1 = dv * a1 + b1[2 * q + 1];
    f16x2 op; op.x = (f16)fmaxf(o0, 0.f); op.y = (f16)fmaxf(o1, 0.f);
    ((uint_t*)h1)[(size_t)r * 64 + q] = __builtin_bit_cast(uint_t, op);
}

// ---- K5: placeholder = (dinv*(sum Y2 + Y2_self) + b2) * m --------------
__global__ __launch_bounds__(64) void k5_agg2(const f16* __restrict__ Y2,
        const float* __restrict__ dinv, const float* __restrict__ mf,
        const int* __restrict__ ecnt, const int* __restrict__ edges,
        const float* __restrict__ b2, f16* __restrict__ ph) {
    int r = blockIdx.x, q = threadIdx.x;
    int t = r / M_, base = t * M_;
    const uint_t* Yu = (const uint_t*)Y2;
    f16x2 sp = __builtin_bit_cast(f16x2, Yu[(size_t)r * 64 + q]);
    float a0 = (float)sp.x, a1 = (float)sp.y;
    int ec = ecnt[r]; if (ec > ECAP) ec = ECAP;
    const int4* ep4 = (const int4*)(edges + (size_t)r * ECAP);
    for (int e = 0; e < ec; e += 4) {
        int4 ix = ep4[e >> 2];
        int j1 = (e + 1 < ec) ? ix.y : ix.x;
        int j2 = (e + 2 < ec) ? ix.z : ix.x;
        int j3 = (e + 3 < ec) ? ix.w : ix.x;
        uint_t u0 = Yu[(size_t)(base + ix.x) * 64 + q];
        uint_t u1 = Yu[(size_t)(base + j1) * 64 + q];
        uint_t u2 = Yu[(size_t)(base + j2) * 64 + q];
        uint_t u3 = Yu[(size_t)(base + j3) * 64 + q];
        f16x2 p0 = __builtin_bit_cast(f16x2, u0);
        a0 += (float)p0.x; a1 += (float)p0.y;
        if (e + 1 < ec) { f16x2 p = __builtin_bit_cast(f16x2, u1); a0 += (float)p.x; a1 += (float)p.y; }
        if (e + 2 < ec) { f16x2 p = __builtin_bit_cast(f16x2, u2); a0 += (float)p.x; a1 += (float)p.y; }
        if (e + 3 < ec) { f16x2 p = __builtin_bit_cast(f16x2, u3); a0 += (float)p.x; a1 += (float)p.y; }
    }
    float dv = dinv[r], mr = mf[r];
    f16x2 op;
    op.x = (f16)((dv * a0 + b2[2 * q]) * mr);
    op.y = (f16)((dv * a1 + b2[2 * q + 1]) * mr);
    ((uint_t*)ph)[(size_t)r * 64 + q] = __builtin_bit_cast(uint_t, op);
}

// ---- MFMA GEMM: [TM_ x 128] f16 @ [128 x Ntot] -> f16 ------------------
// 64x64 tile per block, 4 waves, each wave 16 rows x 64 cols.
// Fragment layouts (verified, learn_hip m89/m120): A[m=lane&15][k=quad*8+j],
// B[k=quad*8+j][n=lane&15], C col=lane&15, row=quad*4+reg.
#define ALD 136   // padded LDS leading dim in f16 (272 B = 68 dwords)
__global__ __launch_bounds__(256) void kgemm_mfma(const f16* __restrict__ A,
        const float* __restrict__ Bw, int bTrans, int Ntot, int mode,
        const float* __restrict__ dinv, const float* __restrict__ ba,
        const float* __restrict__ bb, f16* __restrict__ Out) {
    __shared__ f16 As[64 * ALD];
    __shared__ f16 Bs[64 * ALD];
    int m0 = blockIdx.x * 64;
    int n0 = blockIdx.y * 64;
    int tid = threadIdx.x;
    // stage A: 64 rows x 128 k, b128 loads, row-major padded
#pragma unroll
    for (int u = 0; u < 4; ++u) {
        int idx = u * 256 + tid;
        int row = idx >> 4, seg = idx & 15;
        *(f16x8*)&As[row * ALD + seg * 8] =
            *(const f16x8*)(A + (size_t)(m0 + row) * H_ + seg * 8);
    }
    // stage B transposed into Bs[n][k] (f32 -> f16)
    if (bTrans) {   // Bw [Ntot][128]
#pragma unroll
        for (int u = 0; u < 16; ++u) {
            int idx = u * 256 + tid;           // over 64*64 pairs
            int n = idx >> 6, k2 = (idx & 63) * 2;
            float2 v = *(const float2*)(Bw + (size_t)(n0 + n) * H_ + k2);
            f16x2 pk; pk.x = (f16)v.x; pk.y = (f16)v.y;
            *(uint_t*)&Bs[n * ALD + k2] = __builtin_bit_cast(uint_t, pk);
        }
    } else {        // Bw [128][Ntot]
#pragma unroll
        for (int u = 0; u < 16; ++u) {
            int idx = u * 256 + tid;
            int n = idx >> 6, k2 = (idx & 63) * 2;
            f16x2 pk;
            pk.x = (f16)Bw[(size_t)k2 * Ntot + n0 + n];
            pk.y = (f16)Bw[(size_t)(k2 + 1) * Ntot + n0 + n];
            *(uint_t*)&Bs[n * ALD + k2] = __builtin_bit_cast(uint_t, pk);
        }
    }
    __syncthreads();
    int w = tid >> 6, lane = tid & 63;
    int col = lane & 15, quad = lane >> 4;
    f32x4 acc[4] = {};
#pragma unroll
    for (int kk = 0; kk < 4; ++kk) {
        f16x8 af = *(const f16x8*)&As[(w * 16 + col) * ALD + kk * 32 + quad * 8];
#pragma unroll
        for (int nt = 0; nt < 4; ++nt) {
            f16x8 bf = *(const f16x8*)&Bs[(nt * 16 + col) * ALD + kk * 32 + quad * 8];
            acc[nt] = __builtin_amdgcn_mfma_f32_16x16x32_f16(af, bf, acc[nt], 0, 0, 0);
        }
    }
    // epilogue
    if (mode == 0) {
        float dv[4];
#pragma unroll
        for (int reg = 0; reg < 4; ++reg)
            dv[reg] = dinv[m0 + w * 16 + quad * 4 + reg];
#pragma unroll
        for (int nt = 0; nt < 4; ++nt) {
            int n = n0 + nt * 16 + col;
#pragma unroll
            for (int reg = 0; reg < 4; ++reg) {
                int r = m0 + w * 16 + quad * 4 + reg;
                Out[(size_t)r * Ntot + n] = (f16)(dv[reg] * acc[nt][reg]);
            }
        }
    } else {
#pragma unroll
        for (int nt = 0; nt < 4; ++nt) {
            int n = n0 + nt * 16 + col;
            float bias = ba[n] + bb[n];
#pragma unroll
            for (int reg = 0; reg < 4; ++reg) {
                int r = m0 + w * 16 + quad * 4 + reg;
                int t = r / M_, s = r % M_;
                Out[((size_t)s * T_ + t) * G_ + n] = (f16)(acc[nt][reg] + bias);
            }
        }
    }
}

// ---- K7: 20 LSTM chains; quad-split gates, 1 raw barrier/step ----------
// thread: h = tid>>2 (0..127), q = tid&3 (k-chunk AND gate-x owner).
// Each thread: partial dots of ALL 4 gates over its 32-elem k-chunk
// (4 independent fdot2 chains), +x into acc[q]; 2-round shfl_xor butterfly
// over the quad -> all lanes hold all 4 full gate preacts in-register.
__global__ __launch_bounds__(512, 2) void k7_lstm(const float* __restrict__ Whh,
        const f16* __restrict__ xg, f16* __restrict__ lo) {
    __shared__ uint_t hb2[2][H_ / 2];   // double-buffered h (128 f16 each)
    int t = blockIdx.x, tid = threadIdx.x;
    int h = tid >> 2, q = tid & 3;
    f16x2 w0[16], w1[16], w2[16], w3[16];   // gate rows, this k-chunk
    {
        const float* base = Whh + (size_t)h * H_ + q * 32;
#pragma unroll
        for (int d = 0; d < 16; ++d) {
            f16x2 p;
            p.x = (f16)base[0 * G_ * 32 + 2 * d];       // gate 0 row h
            p.y = (f16)base[0 * G_ * 32 + 2 * d + 1];
            w0[d] = p;
            p.x = (f16)base[(size_t)H_ * H_ + 2 * d];   // gate 1 row 128+h
            p.y = (f16)base[(size_t)H_ * H_ + 2 * d + 1];
            w1[d] = p;
            p.x = (f16)base[(size_t)2 * H_ * H_ + 2 * d];
            p.y = (f16)base[(size_t)2 * H_ * H_ + 2 * d + 1];
            w2[d] = p;
            p.x = (f16)base[(size_t)3 * H_ * H_ + 2 * d];
            p.y = (f16)base[(size_t)3 * H_ * H_ + 2 * d + 1];
            w3[d] = p;
        }
    }
    if (tid < H_ / 2) hb2[0][tid] = 0;
    float cst = 0.f;
    const ushort_t* xpu = (const ushort_t*)xg + t * G_ + q * H_ + h;
    ushort_t xa[8], xb[8];
#pragma unroll
    for (int k = 0; k < 8; ++k) xa[k] = xpu[(size_t)k * TG_];
    __syncthreads();

#define LSTM_STEP(S, XV)                                                      \
    do {                                                                      \
        const uint4* hbp = (const uint4*)&hb2[(S) & 1][0];                    \
        float a0 = 0.f, a1 = 0.f, a2 = 0.f, a3 = 0.f;                         \
        _Pragma("unroll")                                                     \
        for (int d = 0; d < 4; ++d) {                                         \
            uint4 hv = hbp[q * 4 + d];                                        \
            f16x2 e0 = __builtin_bit_cast(f16x2, hv.x);                       \
            f16x2 e1 = __builtin_bit_cast(f16x2, hv.y);                       \
            f16x2 e2 = __builtin_bit_cast(f16x2, hv.z);                       \
            f16x2 e3 = __builtin_bit_cast(f16x2, hv.w);                       \
            a0 = fdot2_(w0[4 * d + 3], e3, fdot2_(w0[4 * d + 2], e2,          \
                 fdot2_(w0[4 * d + 1], e1, fdot2_(w0[4 * d + 0], e0, a0))));  \
            a1 = fdot2_(w1[4 * d + 3], e3, fdot2_(w1[4 * d + 2], e2,          \
                 fdot2_(w1[4 * d + 1], e1, fdot2_(w1[4 * d + 0], e0, a1))));  \
            a2 = fdot2_(w2[4 * d + 3], e3, fdot2_(w2[4 * d + 2], e2,          \
                 fdot2_(w2[4 * d + 1], e1, fdot2_(w2[4 * d + 0], e0, a2))));  \
            a3 = fdot2_(w3[4 * d + 3], e3, fdot2_(w3[4 * d + 2], e2,          \
                 fdot2_(w3[4 * d + 1], e1, fdot2_(w3[4 * d + 0], e0, a3))));  \
        }                                                                     \
        float xf = (float)__builtin_bit_cast(f16, (ushort_t)(XV));            \
        a0 += (q == 0) ? xf : 0.f;                                            \
        a1 += (q == 1) ? xf : 0.f;                                            \
        a2 += (q == 2) ? xf : 0.f;                                            \
        a3 += (q == 3) ? xf : 0.f;                                            \
        a0 += __shfl_xor(a0, 1); a0 += __shfl_xor(a0, 2);                     \
        a1 += __shfl_xor(a1, 1); a1 += __shfl_xor(a1, 2);                     \
        a2 += __shfl_xor(a2, 1); a2 += __shfl_xor(a2, 2);                     \
        a3 += __shfl_xor(a3, 1); a3 += __shfl_xor(a3, 2);                     \
        float gi = fast_sig(a0), gf = fast_sig(a1);                           \
        float gg = fast_tanh(a2), go = fast_sig(a3);                          \
        cst = gf * cst + gi * gg;                                             \
        float hv_ = go * fast_tanh(cst);                                      \
        if (q == 0) {                                                         \
            f16 hh = (f16)hv_;                                                \
            ((ushort_t*)&hb2[((S) & 1) ^ 1][0])[h] =                          \
                __builtin_bit_cast(ushort_t, hh);                             \
            lo[((size_t)(S) * T_ + t) * H_ + h] = hh;                         \
        }                                                                     \
        BARRAW();                                                             \
    } while (0)

    for (int c2 = 0; c2 < 125; ++c2) {
        int sA = c2 * 16;
#pragma unroll
        for (int k = 0; k < 8; ++k) xb[k] = xpu[(size_t)(sA + 8 + k) * TG_];
#pragma unroll
        for (int k = 0; k < 8; ++k) LSTM_STEP(sA + k, xa[k]);
        int nbs = (sA + 16 <= M_ - 8) ? sA + 16 : M_ - 8;
#pragma unroll
        for (int k = 0; k < 8; ++k) xa[k] = xpu[(size_t)(nbs + k) * TG_];
#pragma unroll
        for (int k = 0; k < 8; ++k) LSTM_STEP(sA + 8 + k, xb[k]);
    }
#undef LSTM_STEP
}

// ---- K8: fc1(relu)+fc2; weights in VGPRs; stream 4 rows/iter -----------
__global__ __launch_bounds__(256) void k8_fc(const f16* __restrict__ lo,
        const float* __restrict__ w1, const float* __restrict__ fb1,
        const float* __restrict__ w2, const float* __restrict__ fb2,
        float* __restrict__ out) {
    __shared__ uint_t hl[4][H_ / 2];   // 4 rows x 128 f16
    __shared__ float o1f[4][H2_];
    int tid = threadIdx.x;
    int o = tid & 63, rr = tid >> 6;
    f16x2 w1c[64];
#pragma unroll
    for (int d = 0; d < 64; ++d) {
        f16x2 p;
        p.x = (f16)w1[(2 * d) * H2_ + o];
        p.y = (f16)w1[(2 * d + 1) * H2_ + o];
        w1c[d] = p;
    }
    int o2 = o & 31;
    float w2f[64];
#pragma unroll
    for (int d = 0; d < 64; ++d) w2f[d] = w2[d * OUT_ + o2];
    float fb1v = fb1[o], fb2v = fb2[o2];

    for (int r0 = blockIdx.x * 4; r0 < TM_; r0 += 512 * 4) {
        {
            int row = tid >> 6, qq = tid & 63;
            hl[row][qq] = ((const uint_t*)lo)[(size_t)(r0 + row) * 64 + qq];
        }
        __syncthreads();
        float acc = fb1v;
        const uint4* hb = (const uint4*)&hl[rr][0];
#pragma unroll
        for (int d = 0; d < 16; ++d) {
            uint4 hv = hb[d];
            acc = fdot2_(w1c[4 * d + 0], __builtin_bit_cast(f16x2, hv.x), acc);
            acc = fdot2_(w1c[4 * d + 1], __builtin_bit_cast(f16x2, hv.y), acc);
            acc = fdot2_(w1c[4 * d + 2], __builtin_bit_cast(f16x2, hv.z), acc);
            acc = fdot2_(w1c[4 * d + 3], __builtin_bit_cast(f16x2, hv.w), acc);
        }
        o1f[rr][o] = fmaxf(acc, 0.f);
        __syncthreads();
        if (o < OUT_) {
            float a2 = fb2v;
            const float4* ob = (const float4*)&o1f[rr][0];
#pragma unroll
            for (int d = 0; d < 16; ++d) {
                float4 v = ob[d];
                a2 += v.x * w2f[4 * d + 0] + v.y * w2f[4 * d + 1]
                    + v.z * w2f[4 * d + 2] + v.w * w2f[4 * d + 3];
            }
            out[(size_t)(r0 + rr) * OUT_ + o] = a2;
        }
        __syncthreads();
    }
}

extern "C" void kernel_launch(void* const* d_in, const int* in_sizes, int n_in,
                              void* d_out, int out_size, void* d_ws, size_t ws_size,
                              hipStream_t stream) {
    const float* positions = (const float*)d_in[0];
    const float* adjacency = (const float*)d_in[1];
    const void*  ego       = d_in[2];
    const float* W1   = (const float*)d_in[3];
    const float* b1   = (const float*)d_in[4];
    const float* W2   = (const float*)d_in[5];
    const float* b2   = (const float*)d_in[6];
    const float* W_ih = (const float*)d_in[7];
    const float* W_hh = (const float*)d_in[8];
    const float* b_ih = (const float*)d_in[9];
    const float* b_hh = (const float*)d_in[10];
    const float* fc1w = (const float*)d_in[11];
    const float* fc1b = (const float*)d_in[12];
    const float* fc2w = (const float*)d_in[13];
    const float* fc2b = (const float*)d_in[14];
    float* out = (float*)d_out;

    char* p = (char*)d_ws;
    auto alloc = [&](size_t bytes) {
        void* r = (void*)p;
        p += (bytes + 255) & ~(size_t)255;
        return r;
    };
    float* mf    = (float*)alloc((size_t)TM_ * 4);
    float* dinv  = (float*)alloc((size_t)TM_ * 4);
    int*   ecnt  = (int*)alloc((size_t)TM_ * 4);
    int*   edges = (int*)alloc((size_t)TM_ * ECAP * 4);   // aliased by lo later
    f16*   bufC  = (f16*)alloc((size_t)TM_ * H_ * 2);     // Y1, then Y2
    f16*   bufD  = (f16*)alloc((size_t)TM_ * H_ * 2);     // h1, then ph
    f16*   xg    = (f16*)alloc((size_t)TM_ * G_ * 2);
    f16*   Y1 = bufC, *Y2 = bufC;
    f16*   h1 = bufD, *ph = bufD;
    f16*   lo = (f16*)edges;    // edges dead after k5

    hipLaunchKernelGGL(k0_mask, dim3(40), dim3(1024), 0, stream, ego, mf, ecnt);
    hipLaunchKernelGGL(k1_scan, dim3(8, 20, 10), dim3(256), 0, stream,
                       adjacency, mf, ecnt, edges);
    hipLaunchKernelGGL(k2_y1, dim3(20000), dim3(256), 0, stream,
                       positions, W1, mf, ecnt, dinv, Y1);
    hipLaunchKernelGGL(k3_agg1, dim3(40000), dim3(64), 0, stream,
                       Y1, dinv, ecnt, edges, b1, h1);
    hipLaunchKernelGGL(kgemm_mfma, dim3(625, 2), dim3(256), 0, stream,
                       h1, W2, 0, 128, 0, dinv, (const float*)nullptr,
                       (const float*)nullptr, Y2);
    hipLaunchKernelGGL(k5_agg2, dim3(40000), dim3(64), 0, stream,
                       Y2, dinv, mf, ecnt, edges, b2, ph);
    hipLaunchKernelGGL(kgemm_mfma, dim3(625, 8), dim3(256), 0, stream,
                       ph, W_ih, 1, 512, 1, dinv, b_ih, b_hh, xg);
    hipLaunchKernelGGL(k7_lstm, dim3(20), dim3(512), 0, stream, W_hh, xg, lo);
    hipLaunchKernelGGL(k8_fc, dim3(512), dim3(256), 0, stream,
                       lo, fc1w, fc1b, fc2w, fc2b, out);
}

// Round 5
// 1819.187 us; speedup vs baseline: 1.0543x; 1.0543x over previous
//
#include <hip/hip_runtime.h>
#include <hip/hip_bf16.h>

#define T_   20
#define B_   4
#define NN_  500
#define M_   2000
#define TM_  40000   // T_*M_
#define H_   128
#define G_   512     // 4*H_
#define H2_  64
#define OUT_ 32
#define ECAP 64
#define TG_  (T_ * G_)

typedef unsigned short ushort_t;
typedef unsigned int   uint_t;
typedef _Float16       f16;
typedef f16 f16x2 __attribute__((ext_vector_type(2)));
typedef f16 f16x8 __attribute__((ext_vector_type(8)));
typedef float f32x4 __attribute__((ext_vector_type(4)));

#if defined(__has_builtin)
#  if __has_builtin(__builtin_amdgcn_fdot2)
#    define HAVE_FDOT2 1
#  endif
#endif

__device__ inline float fdot2_(f16x2 a, f16x2 b, float c) {
#ifdef HAVE_FDOT2
    return __builtin_amdgcn_fdot2(a, b, c, false);
#else
    return c + (float)a.x * (float)b.x + (float)a.y * (float)b.y;
#endif
}

__device__ inline float fast_sig(float x) {
    float e = __builtin_amdgcn_exp2f(x * -1.4426950408889634f);
    return __builtin_amdgcn_rcpf(1.f + e);
}
__device__ inline float fast_tanh(float x) {
    float e = __builtin_amdgcn_exp2f(x * 2.8853900817779268f);
    return 1.f - 2.f * __builtin_amdgcn_rcpf(e + 1.f);
}

// raw barrier: no compiler-inserted s_waitcnt vmcnt(0) drain.
// LDS pipe is in-order per CU (validated R3/R4: correct results).
#define BARRAW() asm volatile("s_barrier" ::: "memory")

// ---- K0: detect ego dtype + build mask[t][i] + zero ecnt ---------------
__global__ __launch_bounds__(1024) void k0_mask(const void* __restrict__ ego,
                                                float* __restrict__ mf,
                                                int* __restrict__ ecnt) {
    __shared__ int fl[3];
    int tid = threadIdx.x;
    if (tid < 3) fl[tid] = 0;
    __syncthreads();
    const uint_t* dw = (const uint_t*)ego;
    int a = 0, b = 0, c = 0;
    for (int i = tid; i < 2500; i += 1024) {   // 10 KB <= any dtype's size
        uint_t v = dw[i];
        bool isf32  = (v == 0x3F800000u);
        bool isbf16 = (v == 0x00003F80u) || (v == 0x3F803F80u);
        if (isf32)  a = 1;
        if (isbf16) b = 1;
        if (v > 1u && !isf32 && !isbf16) c = 1;
    }
    if (a) fl[0] = 1;
    if (b) fl[1] = 1;
    if (c) fl[2] = 1;
    __syncthreads();
    int mode;                       // 0=int32, 1=uint8, 2=f32, 3=bf16
    if (fl[1])      mode = 3;
    else if (fl[0]) mode = 2;
    else if (fl[2]) mode = 1;
    else            mode = 0;
    int e = blockIdx.x * 1024 + tid;
    if (e >= TM_) return;
    ecnt[e] = 0;
    int t = e / M_, i = e % M_;
    int bb = i / NN_, n = i % NN_;
    int src = (bb * T_ + t) * NN_ + n;
    bool on;
    if (mode == 0)      on = ((const int*)ego)[src] != 0;
    else if (mode == 1) on = ((const unsigned char*)ego)[src] != 0;
    else if (mode == 2) on = ((const float*)ego)[src] != 0.f;
    else                on = ((const ushort_t*)ego)[src] != 0;
    mf[e] = on ? 1.f : 0.f;
}

// ---- K1: strip-parallel adjacency scan, atomic slot alloc --------------
#define JSTRIP 200
__global__ void k1_scan(const float* __restrict__ adj, const float* __restrict__ mf,
                        int* __restrict__ ecnt, int* __restrict__ edges) {
    __shared__ float ms[JSTRIP];
    int t = blockIdx.y, j0 = blockIdx.z * JSTRIP;
    int i = blockIdx.x * 256 + threadIdx.x;
    for (int idx = threadIdx.x; idx < JSTRIP; idx += 256)
        ms[idx] = mf[t * M_ + j0 + idx];
    __syncthreads();
    if (i >= M_) return;
    if (mf[t * M_ + i] == 0.f) return;          // masked column: no edges
    const float* ap = adj + (size_t)t * M_ * M_ + (size_t)j0 * M_ + i;
    int r = t * M_ + i;
    int* ep = edges + (size_t)r * ECAP;
#pragma unroll 8
    for (int jj = 0; jj < JSTRIP; ++jj) {
        float av = ap[(size_t)jj * M_];
        if (av != 0.f && ms[jj] != 0.f) {
            int pos = atomicAdd(&ecnt[r], 1);
            if (pos < ECAP) ep[pos] = j0 + jj;
        }
    }
}

// ---- K2: dinv from ecnt/mf; Y1 = dinv * (x @ W1) -----------------------
__global__ void k2_y1(const float* __restrict__ pos, const float* __restrict__ W1,
                      const float* __restrict__ mf, const int* __restrict__ ecnt,
                      float* __restrict__ dinv, f16* __restrict__ Y1) {
    int gid = blockIdx.x * 256 + threadIdx.x;    // over TM_*H_
    int r = gid >> 7, h = gid & 127;
    if (r >= TM_) return;
    float mr = mf[r];
    int cnt = ecnt[r];
    float dv = (mr != 0.f) ? __frsqrt_rn((float)(cnt + 1)) : 0.f;
    if (h == 0) dinv[r] = dv;
    float2 xy = ((const float2*)pos)[r];
    float v = xy.x * W1[h] + xy.y * W1[H_ + h];
    Y1[gid] = (f16)(dv * v);
}

// ---- K3: h1 = relu(dinv*(sum_edges Y1 + Y1_self) + b1), f16x2 lanes ----
__global__ __launch_bounds__(64) void k3_agg1(const f16* __restrict__ Y1,
        const float* __restrict__ dinv, const int* __restrict__ ecnt,
        const int* __restrict__ edges, const float* __restrict__ b1,
        f16* __restrict__ h1) {
    int r = blockIdx.x, q = threadIdx.x;   // q: h-pair index 0..63
    int t = r / M_, base = t * M_;
    const uint_t* Yu = (const uint_t*)Y1;
    f16x2 sp = __builtin_bit_cast(f16x2, Yu[(size_t)r * 64 + q]);
    float a0 = (float)sp.x, a1 = (float)sp.y;
    int ec = ecnt[r]; if (ec > ECAP) ec = ECAP;
    const int4* ep4 = (const int4*)(edges + (size_t)r * ECAP);
    for (int e = 0; e < ec; e += 4) {
        int4 ix = ep4[e >> 2];
        int j1 = (e + 1 < ec) ? ix.y : ix.x;
        int j2 = (e + 2 < ec) ? ix.z : ix.x;
        int j3 = (e + 3 < ec) ? ix.w : ix.x;
        uint_t u0 = Yu[(size_t)(base + ix.x) * 64 + q];
        uint_t u1 = Yu[(size_t)(base + j1) * 64 + q];
        uint_t u2 = Yu[(size_t)(base + j2) * 64 + q];
        uint_t u3 = Yu[(size_t)(base + j3) * 64 + q];
        f16x2 p0 = __builtin_bit_cast(f16x2, u0);
        a0 += (float)p0.x; a1 += (float)p0.y;
        if (e + 1 < ec) { f16x2 p = __builtin_bit_cast(f16x2, u1); a0 += (float)p.x; a1 += (float)p.y; }
        if (e + 2 < ec) { f16x2 p = __builtin_bit_cast(f16x2, u2); a0 += (float)p.x; a1 += (float)p.y; }
        if (e + 3 < ec) { f16x2 p = __builtin_bit_cast(f16x2, u3); a0 += (float)p.x; a1 += (float)p.y; }
    }
    float dv = dinv[r];
    float o0 = dv * a0 + b1[2 * q];
    float o1 = dv * a1 + b1[2 * q + 1];
    f16x2 op; op.x = (f16)fmaxf(o0, 0.f); op.y = (f16)fmaxf(o1, 0.f);
    ((uint_t*)h1)[(size_t)r * 64 + q] = __builtin_bit_cast(uint_t, op);
}

// ---- K5: placeholder = (dinv*(sum Y2 + Y2_self) + b2) * m --------------
__global__ __launch_bounds__(64) void k5_agg2(const f16* __restrict__ Y2,
        const float* __restrict__ dinv, const float* __restrict__ mf,
        const int* __restrict__ ecnt, const int* __restrict__ edges,
        const float* __restrict__ b2, f16* __restrict__ ph) {
    int r = blockIdx.x, q = threadIdx.x;
    int t = r / M_, base = t * M_;
    const uint_t* Yu = (const uint_t*)Y2;
    f16x2 sp = __builtin_bit_cast(f16x2, Yu[(size_t)r * 64 + q]);
    float a0 = (float)sp.x, a1 = (float)sp.y;
    int ec = ecnt[r]; if (ec > ECAP) ec = ECAP;
    const int4* ep4 = (const int4*)(edges + (size_t)r * ECAP);
    for (int e = 0; e < ec; e += 4) {
        int4 ix = ep4[e >> 2];
        int j1 = (e + 1 < ec) ? ix.y : ix.x;
        int j2 = (e + 2 < ec) ? ix.z : ix.x;
        int j3 = (e + 3 < ec) ? ix.w : ix.x;
        uint_t u0 = Yu[(size_t)(base + ix.x) * 64 + q];
        uint_t u1 = Yu[(size_t)(base + j1) * 64 + q];
        uint_t u2 = Yu[(size_t)(base + j2) * 64 + q];
        uint_t u3 = Yu[(size_t)(base + j3) * 64 + q];
        f16x2 p0 = __builtin_bit_cast(f16x2, u0);
        a0 += (float)p0.x; a1 += (float)p0.y;
        if (e + 1 < ec) { f16x2 p = __builtin_bit_cast(f16x2, u1); a0 += (float)p.x; a1 += (float)p.y; }
        if (e + 2 < ec) { f16x2 p = __builtin_bit_cast(f16x2, u2); a0 += (float)p.x; a1 += (float)p.y; }
        if (e + 3 < ec) { f16x2 p = __builtin_bit_cast(f16x2, u3); a0 += (float)p.x; a1 += (float)p.y; }
    }
    float dv = dinv[r], mr = mf[r];
    f16x2 op;
    op.x = (f16)((dv * a0 + b2[2 * q]) * mr);
    op.y = (f16)((dv * a1 + b2[2 * q + 1]) * mr);
    ((uint_t*)ph)[(size_t)r * 64 + q] = __builtin_bit_cast(uint_t, op);
}

// ---- MFMA GEMM: [TM_ x 128] f16 @ [128 x Ntot] -> f16 ------------------
// 64x64 tile per block, 4 waves, each wave 16 rows x 64 cols.
// mode=1 now stores xg GATE-INTERLEAVED: xg[(s*T+t)*G + (n&127)*4 + (n>>7)]
// so k7's thread (m,p) reads its two x-values as one b32.
#define ALD 136   // padded LDS leading dim in f16
__global__ __launch_bounds__(256) void kgemm_mfma(const f16* __restrict__ A,
        const float* __restrict__ Bw, int bTrans, int Ntot, int mode,
        const float* __restrict__ dinv, const float* __restrict__ ba,
        const float* __restrict__ bb, f16* __restrict__ Out) {
    __shared__ f16 As[64 * ALD];
    __shared__ f16 Bs[64 * ALD];
    int m0 = blockIdx.x * 64;
    int n0 = blockIdx.y * 64;
    int tid = threadIdx.x;
#pragma unroll
    for (int u = 0; u < 4; ++u) {
        int idx = u * 256 + tid;
        int row = idx >> 4, seg = idx & 15;
        *(f16x8*)&As[row * ALD + seg * 8] =
            *(const f16x8*)(A + (size_t)(m0 + row) * H_ + seg * 8);
    }
    if (bTrans) {   // Bw [Ntot][128]
#pragma unroll
        for (int u = 0; u < 16; ++u) {
            int idx = u * 256 + tid;
            int n = idx >> 6, k2 = (idx & 63) * 2;
            float2 v = *(const float2*)(Bw + (size_t)(n0 + n) * H_ + k2);
            f16x2 pk; pk.x = (f16)v.x; pk.y = (f16)v.y;
            *(uint_t*)&Bs[n * ALD + k2] = __builtin_bit_cast(uint_t, pk);
        }
    } else {        // Bw [128][Ntot]
#pragma unroll
        for (int u = 0; u < 16; ++u) {
            int idx = u * 256 + tid;
            int n = idx >> 6, k2 = (idx & 63) * 2;
            f16x2 pk;
            pk.x = (f16)Bw[(size_t)k2 * Ntot + n0 + n];
            pk.y = (f16)Bw[(size_t)(k2 + 1) * Ntot + n0 + n];
            *(uint_t*)&Bs[n * ALD + k2] = __builtin_bit_cast(uint_t, pk);
        }
    }
    __syncthreads();
    int w = tid >> 6, lane = tid & 63;
    int col = lane & 15, quad = lane >> 4;
    f32x4 acc[4] = {};
#pragma unroll
    for (int kk = 0; kk < 4; ++kk) {
        f16x8 af = *(const f16x8*)&As[(w * 16 + col) * ALD + kk * 32 + quad * 8];
#pragma unroll
        for (int nt = 0; nt < 4; ++nt) {
            f16x8 bf = *(const f16x8*)&Bs[(nt * 16 + col) * ALD + kk * 32 + quad * 8];
            acc[nt] = __builtin_amdgcn_mfma_f32_16x16x32_f16(af, bf, acc[nt], 0, 0, 0);
        }
    }
    if (mode == 0) {
        float dv[4];
#pragma unroll
        for (int reg = 0; reg < 4; ++reg)
            dv[reg] = dinv[m0 + w * 16 + quad * 4 + reg];
#pragma unroll
        for (int nt = 0; nt < 4; ++nt) {
            int n = n0 + nt * 16 + col;
#pragma unroll
            for (int reg = 0; reg < 4; ++reg) {
                int r = m0 + w * 16 + quad * 4 + reg;
                Out[(size_t)r * Ntot + n] = (f16)(dv[reg] * acc[nt][reg]);
            }
        }
    } else {
#pragma unroll
        for (int nt = 0; nt < 4; ++nt) {
            int n = n0 + nt * 16 + col;
            float bias = ba[n] + bb[n];
            int pos = (n & 127) * 4 + (n >> 7);   // gate-interleaved slot
#pragma unroll
            for (int reg = 0; reg < 4; ++reg) {
                int r = m0 + w * 16 + quad * 4 + reg;
                int t = r / M_, s = r % M_;
                Out[((size_t)s * T_ + t) * G_ + pos] = (f16)(acc[nt][reg] + bias);
            }
        }
    }
}

// ---- K7: 20 LSTM chains; 4 waves, pair-split gates, 1 barrier/step -----
// thread (m = tid>>1, p = tid&1): p0 owns gates (i,f) of h-index m,
// p1 owns (g,o). One shfl_xor(1) pair exchanges acts; both lanes keep
// c redundantly (identical ops -> deterministic). h double-buffered.
__global__ __launch_bounds__(256, 1) void k7_lstm(const float* __restrict__ Whh,
        const f16* __restrict__ xg, f16* __restrict__ lo) {
    __shared__ uint_t hb2[2][H_ / 2];   // double-buffered h (128 f16 each)
    int t = blockIdx.x, tid = threadIdx.x;
    int m = tid >> 1, p = tid & 1;
    int n1 = p ? (2 * H_ + m) : m;      // row of W_hh: p0->i, p1->g
    int n2 = n1 + H_;                   // p0->f, p1->o
    f16x2 wA[64], wB[64];
    {
        const float* rA = Whh + (size_t)n1 * H_;
        const float* rB = Whh + (size_t)n2 * H_;
#pragma unroll
        for (int d = 0; d < 64; ++d) {
            f16x2 a, b;
            a.x = (f16)rA[2 * d]; a.y = (f16)rA[2 * d + 1];
            b.x = (f16)rB[2 * d]; b.y = (f16)rB[2 * d + 1];
            wA[d] = a; wB[d] = b;
        }
    }
    if (tid < H_ / 2) hb2[0][tid] = 0;
    float cst = 0.f;
    // xg gate-interleaved: uint index (s*T+t)*256 + m*2 + p
    const uint_t* xpu = (const uint_t*)xg + t * (G_ / 2) + m * 2 + p;
    uint_t xa[8], xb[8];
#pragma unroll
    for (int k = 0; k < 8; ++k) xa[k] = xpu[(size_t)k * (TG_ / 2)];
    __syncthreads();

#define LSTM_STEP(S, XV)                                                      \
    do {                                                                      \
        const uint4* hbp = (const uint4*)&hb2[(S) & 1][0];                    \
        float cA0 = 0.f, cA1 = 0.f, cA2 = 0.f, cA3 = 0.f;                     \
        float cB0 = 0.f, cB1 = 0.f, cB2 = 0.f, cB3 = 0.f;                     \
        _Pragma("unroll")                                                     \
        for (int d = 0; d < 4; ++d) {                                         \
            uint4 h0 = hbp[4 * d + 0];                                        \
            uint4 h1v = hbp[4 * d + 1];                                       \
            uint4 h2v = hbp[4 * d + 2];                                       \
            uint4 h3v = hbp[4 * d + 3];                                       \
            f16x2 e;                                                          \
            e = __builtin_bit_cast(f16x2, h0.x);                              \
            cA0 = fdot2_(wA[16 * d + 0], e, cA0); cB0 = fdot2_(wB[16 * d + 0], e, cB0); \
            e = __builtin_bit_cast(f16x2, h0.y);                              \
            cA0 = fdot2_(wA[16 * d + 1], e, cA0); cB0 = fdot2_(wB[16 * d + 1], e, cB0); \
            e = __builtin_bit_cast(f16x2, h0.z);                              \
            cA0 = fdot2_(wA[16 * d + 2], e, cA0); cB0 = fdot2_(wB[16 * d + 2], e, cB0); \
            e = __builtin_bit_cast(f16x2, h0.w);                              \
            cA0 = fdot2_(wA[16 * d + 3], e, cA0); cB0 = fdot2_(wB[16 * d + 3], e, cB0); \
            e = __builtin_bit_cast(f16x2, h1v.x);                             \
            cA1 = fdot2_(wA[16 * d + 4], e, cA1); cB1 = fdot2_(wB[16 * d + 4], e, cB1); \
            e = __builtin_bit_cast(f16x2, h1v.y);                             \
            cA1 = fdot2_(wA[16 * d + 5], e, cA1); cB1 = fdot2_(wB[16 * d + 5], e, cB1); \
            e = __builtin_bit_cast(f16x2, h1v.z);                             \
            cA1 = fdot2_(wA[16 * d + 6], e, cA1); cB1 = fdot2_(wB[16 * d + 6], e, cB1); \
            e = __builtin_bit_cast(f16x2, h1v.w);                             \
            cA1 = fdot2_(wA[16 * d + 7], e, cA1); cB1 = fdot2_(wB[16 * d + 7], e, cB1); \
            e = __builtin_bit_cast(f16x2, h2v.x);                             \
            cA2 = fdot2_(wA[16 * d + 8], e, cA2); cB2 = fdot2_(wB[16 * d + 8], e, cB2); \
            e = __builtin_bit_cast(f16x2, h2v.y);                             \
            cA2 = fdot2_(wA[16 * d + 9], e, cA2); cB2 = fdot2_(wB[16 * d + 9], e, cB2); \
            e = __builtin_bit_cast(f16x2, h2v.z);                             \
            cA2 = fdot2_(wA[16 * d + 10], e, cA2); cB2 = fdot2_(wB[16 * d + 10], e, cB2); \
            e = __builtin_bit_cast(f16x2, h2v.w);                             \
            cA2 = fdot2_(wA[16 * d + 11], e, cA2); cB2 = fdot2_(wB[16 * d + 11], e, cB2); \
            e = __builtin_bit_cast(f16x2, h3v.x);                             \
            cA3 = fdot2_(wA[16 * d + 12], e, cA3); cB3 = fdot2_(wB[16 * d + 12], e, cB3); \
            e = __builtin_bit_cast(f16x2, h3v.y);                             \
            cA3 = fdot2_(wA[16 * d + 13], e, cA3); cB3 = fdot2_(wB[16 * d + 13], e, cB3); \
            e = __builtin_bit_cast(f16x2, h3v.z);                             \
            cA3 = fdot2_(wA[16 * d + 14], e, cA3); cB3 = fdot2_(wB[16 * d + 14], e, cB3); \
            e = __builtin_bit_cast(f16x2, h3v.w);                             \
            cA3 = fdot2_(wA[16 * d + 15], e, cA3); cB3 = fdot2_(wB[16 * d + 15], e, cB3); \
        }                                                                     \
        f16x2 xp = __builtin_bit_cast(f16x2, (uint_t)(XV));                   \
        float sA = (cA0 + cA1) + (cA2 + cA3) + (float)xp.x;                   \
        float sB = (cB0 + cB1) + (cB2 + cB3) + (float)xp.y;                   \
        float actA = p ? fast_tanh(sA) : fast_sig(sA);                        \
        float actB = fast_sig(sB);                                            \
        float oA = __shfl_xor(actA, 1);                                       \
        float oB = __shfl_xor(actB, 1);                                       \
        float gi = p ? oA : actA;                                             \
        float gf = p ? oB : actB;                                             \
        float gg = p ? actA : oA;                                             \
        float go = p ? actB : oB;                                             \
        cst = gf * cst + gi * gg;                                             \
        float hv_ = go * fast_tanh(cst);                                      \
        f16 hh = (f16)hv_;                                                    \
        if (p == 0)                                                           \
            ((ushort_t*)&hb2[((S) & 1) ^ 1][0])[m] =                          \
                __builtin_bit_cast(ushort_t, hh);                             \
        else                                                                  \
            lo[((size_t)(S) * T_ + t) * H_ + m] = hh;                         \
        BARRAW();                                                             \
    } while (0)

    for (int c2 = 0; c2 < 125; ++c2) {
        int s0 = c2 * 16;
#pragma unroll
        for (int k = 0; k < 8; ++k) xb[k] = xpu[(size_t)(s0 + 8 + k) * (TG_ / 2)];
#pragma unroll
        for (int k = 0; k < 8; ++k) LSTM_STEP(s0 + k, xa[k]);
        int nbs = (s0 + 16 <= M_ - 8) ? s0 + 16 : M_ - 8;
#pragma unroll
        for (int k = 0; k < 8; ++k) xa[k] = xpu[(size_t)(nbs + k) * (TG_ / 2)];
#pragma unroll
        for (int k = 0; k < 8; ++k) LSTM_STEP(s0 + 8 + k, xb[k]);
    }
#undef LSTM_STEP
}

// ---- K8: fc1(relu)+fc2; weights in VGPRs; stream 4 rows/iter -----------
__global__ __launch_bounds__(256) void k8_fc(const f16* __restrict__ lo,
        const float* __restrict__ w1, const float* __restrict__ fb1,
        const float* __restrict__ w2, const float* __restrict__ fb2,
        float* __restrict__ out) {
    __shared__ uint_t hl[4][H_ / 2];   // 4 rows x 128 f16
    __shared__ float o1f[4][H2_];
    int tid = threadIdx.x;
    int o = tid & 63, rr = tid >> 6;
    f16x2 w1c[64];
#pragma unroll
    for (int d = 0; d < 64; ++d) {
        f16x2 p;
        p.x = (f16)w1[(2 * d) * H2_ + o];
        p.y = (f16)w1[(2 * d + 1) * H2_ + o];
        w1c[d] = p;
    }
    int o2 = o & 31;
    float w2f[64];
#pragma unroll
    for (int d = 0; d < 64; ++d) w2f[d] = w2[d * OUT_ + o2];
    float fb1v = fb1[o], fb2v = fb2[o2];

    for (int r0 = blockIdx.x * 4; r0 < TM_; r0 += 512 * 4) {
        {
            int row = tid >> 6, qq = tid & 63;
            hl[row][qq] = ((const uint_t*)lo)[(size_t)(r0 + row) * 64 + qq];
        }
        __syncthreads();
        float acc = fb1v;
        const uint4* hb = (const uint4*)&hl[rr][0];
#pragma unroll
        for (int d = 0; d < 16; ++d) {
            uint4 hv = hb[d];
            acc = fdot2_(w1c[4 * d + 0], __builtin_bit_cast(f16x2, hv.x), acc);
            acc = fdot2_(w1c[4 * d + 1], __builtin_bit_cast(f16x2, hv.y), acc);
            acc = fdot2_(w1c[4 * d + 2], __builtin_bit_cast(f16x2, hv.z), acc);
            acc = fdot2_(w1c[4 * d + 3], __builtin_bit_cast(f16x2, hv.w), acc);
        }
        o1f[rr][o] = fmaxf(acc, 0.f);
        __syncthreads();
        if (o < OUT_) {
            float a2 = fb2v;
            const float4* ob = (const float4*)&o1f[rr][0];
#pragma unroll
            for (int d = 0; d < 16; ++d) {
                float4 v = ob[d];
                a2 += v.x * w2f[4 * d + 0] + v.y * w2f[4 * d + 1]
                    + v.z * w2f[4 * d + 2] + v.w * w2f[4 * d + 3];
            }
            out[(size_t)(r0 + rr) * OUT_ + o] = a2;
        }
        __syncthreads();
    }
}

extern "C" void kernel_launch(void* const* d_in, const int* in_sizes, int n_in,
                              void* d_out, int out_size, void* d_ws, size_t ws_size,
                              hipStream_t stream) {
    const float* positions = (const float*)d_in[0];
    const float* adjacency = (const float*)d_in[1];
    const void*  ego       = d_in[2];
    const float* W1   = (const float*)d_in[3];
    const float* b1   = (const float*)d_in[4];
    const float* W2   = (const float*)d_in[5];
    const float* b2   = (const float*)d_in[6];
    const float* W_ih = (const float*)d_in[7];
    const float* W_hh = (const float*)d_in[8];
    const float* b_ih = (const float*)d_in[9];
    const float* b_hh = (const float*)d_in[10];
    const float* fc1w = (const float*)d_in[11];
    const float* fc1b = (const float*)d_in[12];
    const float* fc2w = (const float*)d_in[13];
    const float* fc2b = (const float*)d_in[14];
    float* out = (float*)d_out;

    char* p = (char*)d_ws;
    auto alloc = [&](size_t bytes) {
        void* r = (void*)p;
        p += (bytes + 255) & ~(size_t)255;
        return r;
    };
    float* mf    = (float*)alloc((size_t)TM_ * 4);
    float* dinv  = (float*)alloc((size_t)TM_ * 4);
    int*   ecnt  = (int*)alloc((size_t)TM_ * 4);
    int*   edges = (int*)alloc((size_t)TM_ * ECAP * 4);   // aliased by lo later
    f16*   bufC  = (f16*)alloc((size_t)TM_ * H_ * 2);     // Y1, then Y2
    f16*   bufD  = (f16*)alloc((size_t)TM_ * H_ * 2);     // h1, then ph
    f16*   xg    = (f16*)alloc((size_t)TM_ * G_ * 2);
    f16*   Y1 = bufC, *Y2 = bufC;
    f16*   h1 = bufD, *ph = bufD;
    f16*   lo = (f16*)edges;    // edges dead after k5

    hipLaunchKernelGGL(k0_mask, dim3(40), dim3(1024), 0, stream, ego, mf, ecnt);
    hipLaunchKernelGGL(k1_scan, dim3(8, 20, 10), dim3(256), 0, stream,
                       adjacency, mf, ecnt, edges);
    hipLaunchKernelGGL(k2_y1, dim3(20000), dim3(256), 0, stream,
                       positions, W1, mf, ecnt, dinv, Y1);
    hipLaunchKernelGGL(k3_agg1, dim3(40000), dim3(64), 0, stream,
                       Y1, dinv, ecnt, edges, b1, h1);
    hipLaunchKernelGGL(kgemm_mfma, dim3(625, 2), dim3(256), 0, stream,
                       h1, W2, 0, 128, 0, dinv, (const float*)nullptr,
                       (const float*)nullptr, Y2);
    hipLaunchKernelGGL(k5_agg2, dim3(40000), dim3(64), 0, stream,
                       Y2, dinv, mf, ecnt, edges, b2, ph);
    hipLaunchKernelGGL(kgemm_mfma, dim3(625, 8), dim3(256), 0, stream,
                       ph, W_ih, 1, 512, 1, dinv, b_ih, b_hh, xg);
    hipLaunchKernelGGL(k7_lstm, dim3(20), dim3(256), 0, stream, W_hh, xg, lo);
    hipLaunchKernelGGL(k8_fc, dim3(512), dim3(256), 0, stream,
                       lo, fc1w, fc1b, fc2w, fc2b, out);
}

// Round 6
// 1676.218 us; speedup vs baseline: 1.1442x; 1.0853x over previous
//
#include <hip/hip_runtime.h>
#include <hip/hip_bf16.h>

#define T_   20
#define B_   4
#define NN_  500
#define M_   2000
#define TM_  40000   // T_*M_
#define H_   128
#define G_   512     // 4*H_
#define H2_  64
#define OUT_ 32
#define ECAP 64
#define TG_  (T_ * G_)

typedef unsigned short ushort_t;
typedef unsigned int   uint_t;
typedef _Float16       f16;
typedef f16 f16x2 __attribute__((ext_vector_type(2)));
typedef f16 f16x8 __attribute__((ext_vector_type(8)));
typedef float f32x4 __attribute__((ext_vector_type(4)));

#if defined(__has_builtin)
#  if __has_builtin(__builtin_amdgcn_fdot2)
#    define HAVE_FDOT2 1
#  endif
#endif

__device__ inline float fdot2_(f16x2 a, f16x2 b, float c) {
#ifdef HAVE_FDOT2
    return __builtin_amdgcn_fdot2(a, b, c, false);
#else
    return c + (float)a.x * (float)b.x + (float)a.y * (float)b.y;
#endif
}

__device__ inline float fast_sig(float x) {
    float e = __builtin_amdgcn_exp2f(x * -1.4426950408889634f);
    return __builtin_amdgcn_rcpf(1.f + e);
}
__device__ inline float fast_tanh(float x) {
    float e = __builtin_amdgcn_exp2f(x * 2.8853900817779268f);
    return 1.f - 2.f * __builtin_amdgcn_rcpf(e + 1.f);
}

// raw barrier: no compiler-inserted s_waitcnt vmcnt(0) drain.
// LDS pipe is in-order per CU (validated R3/R4/R5: correct results).
#define BARRAW() asm volatile("s_barrier" ::: "memory")

// ---- K0: detect ego dtype + build mask[t][i] + zero ecnt ---------------
__global__ __launch_bounds__(1024) void k0_mask(const void* __restrict__ ego,
                                                float* __restrict__ mf,
                                                int* __restrict__ ecnt) {
    __shared__ int fl[3];
    int tid = threadIdx.x;
    if (tid < 3) fl[tid] = 0;
    __syncthreads();
    const uint_t* dw = (const uint_t*)ego;
    int a = 0, b = 0, c = 0;
    for (int i = tid; i < 2500; i += 1024) {   // 10 KB <= any dtype's size
        uint_t v = dw[i];
        bool isf32  = (v == 0x3F800000u);
        bool isbf16 = (v == 0x00003F80u) || (v == 0x3F803F80u);
        if (isf32)  a = 1;
        if (isbf16) b = 1;
        if (v > 1u && !isf32 && !isbf16) c = 1;
    }
    if (a) fl[0] = 1;
    if (b) fl[1] = 1;
    if (c) fl[2] = 1;
    __syncthreads();
    int mode;                       // 0=int32, 1=uint8, 2=f32, 3=bf16
    if (fl[1])      mode = 3;
    else if (fl[0]) mode = 2;
    else if (fl[2]) mode = 1;
    else            mode = 0;
    int e = blockIdx.x * 1024 + tid;
    if (e >= TM_) return;
    ecnt[e] = 0;
    int t = e / M_, i = e % M_;
    int bb = i / NN_, n = i % NN_;
    int src = (bb * T_ + t) * NN_ + n;
    bool on;
    if (mode == 0)      on = ((const int*)ego)[src] != 0;
    else if (mode == 1) on = ((const unsigned char*)ego)[src] != 0;
    else if (mode == 2) on = ((const float*)ego)[src] != 0.f;
    else                on = ((const ushort_t*)ego)[src] != 0;
    mf[e] = on ? 1.f : 0.f;
}

// ---- K1: strip-parallel adjacency scan, atomic slot alloc --------------
#define JSTRIP 200
__global__ void k1_scan(const float* __restrict__ adj, const float* __restrict__ mf,
                        int* __restrict__ ecnt, int* __restrict__ edges) {
    __shared__ float ms[JSTRIP];
    int t = blockIdx.y, j0 = blockIdx.z * JSTRIP;
    int i = blockIdx.x * 256 + threadIdx.x;
    for (int idx = threadIdx.x; idx < JSTRIP; idx += 256)
        ms[idx] = mf[t * M_ + j0 + idx];
    __syncthreads();
    if (i >= M_) return;
    if (mf[t * M_ + i] == 0.f) return;          // masked column: no edges
    const float* ap = adj + (size_t)t * M_ * M_ + (size_t)j0 * M_ + i;
    int r = t * M_ + i;
    int* ep = edges + (size_t)r * ECAP;
#pragma unroll 8
    for (int jj = 0; jj < JSTRIP; ++jj) {
        float av = ap[(size_t)jj * M_];
        if (av != 0.f && ms[jj] != 0.f) {
            int pos = atomicAdd(&ecnt[r], 1);
            if (pos < ECAP) ep[pos] = j0 + jj;
        }
    }
}

// ---- K2: dinv from ecnt/mf; Y1 = dinv * (x @ W1) -----------------------
__global__ void k2_y1(const float* __restrict__ pos, const float* __restrict__ W1,
                      const float* __restrict__ mf, const int* __restrict__ ecnt,
                      float* __restrict__ dinv, f16* __restrict__ Y1) {
    int gid = blockIdx.x * 256 + threadIdx.x;    // over TM_*H_
    int r = gid >> 7, h = gid & 127;
    if (r >= TM_) return;
    float mr = mf[r];
    int cnt = ecnt[r];
    float dv = (mr != 0.f) ? __frsqrt_rn((float)(cnt + 1)) : 0.f;
    if (h == 0) dinv[r] = dv;
    float2 xy = ((const float2*)pos)[r];
    float v = xy.x * W1[h] + xy.y * W1[H_ + h];
    Y1[gid] = (f16)(dv * v);
}

// ---- K3: h1 = relu(dinv*(sum_edges Y1 + Y1_self) + b1), f16x2 lanes ----
__global__ __launch_bounds__(64) void k3_agg1(const f16* __restrict__ Y1,
        const float* __restrict__ dinv, const int* __restrict__ ecnt,
        const int* __restrict__ edges, const float* __restrict__ b1,
        f16* __restrict__ h1) {
    int r = blockIdx.x, q = threadIdx.x;   // q: h-pair index 0..63
    int t = r / M_, base = t * M_;
    const uint_t* Yu = (const uint_t*)Y1;
    f16x2 sp = __builtin_bit_cast(f16x2, Yu[(size_t)r * 64 + q]);
    float a0 = (float)sp.x, a1 = (float)sp.y;
    int ec = ecnt[r]; if (ec > ECAP) ec = ECAP;
    const int4* ep4 = (const int4*)(edges + (size_t)r * ECAP);
    for (int e = 0; e < ec; e += 4) {
        int4 ix = ep4[e >> 2];
        int j1 = (e + 1 < ec) ? ix.y : ix.x;
        int j2 = (e + 2 < ec) ? ix.z : ix.x;
        int j3 = (e + 3 < ec) ? ix.w : ix.x;
        uint_t u0 = Yu[(size_t)(base + ix.x) * 64 + q];
        uint_t u1 = Yu[(size_t)(base + j1) * 64 + q];
        uint_t u2 = Yu[(size_t)(base + j2) * 64 + q];
        uint_t u3 = Yu[(size_t)(base + j3) * 64 + q];
        f16x2 p0 = __builtin_bit_cast(f16x2, u0);
        a0 += (float)p0.x; a1 += (float)p0.y;
        if (e + 1 < ec) { f16x2 p = __builtin_bit_cast(f16x2, u1); a0 += (float)p.x; a1 += (float)p.y; }
        if (e + 2 < ec) { f16x2 p = __builtin_bit_cast(f16x2, u2); a0 += (float)p.x; a1 += (float)p.y; }
        if (e + 3 < ec) { f16x2 p = __builtin_bit_cast(f16x2, u3); a0 += (float)p.x; a1 += (float)p.y; }
    }
    float dv = dinv[r];
    float o0 = dv * a0 + b1[2 * q];
    float o1 = dv * a1 + b1[2 * q + 1];
    f16x2 op; op.x = (f16)fmaxf(o0, 0.f); op.y = (f16)fmaxf(o1, 0.f);
    ((uint_t*)h1)[(size_t)r * 64 + q] = __builtin_bit_cast(uint_t, op);
}

// ---- K5: placeholder = (dinv*(sum Y2 + Y2_self) + b2) * m --------------
__global__ __launch_bounds__(64) void k5_agg2(const f16* __restrict__ Y2,
        const float* __restrict__ dinv, const float* __restrict__ mf,
        const int* __restrict__ ecnt, const int* __restrict__ edges,
        const float* __restrict__ b2, f16* __restrict__ ph) {
    int r = blockIdx.x, q = threadIdx.x;
    int t = r / M_, base = t * M_;
    const uint_t* Yu = (const uint_t*)Y2;
    f16x2 sp = __builtin_bit_cast(f16x2, Yu[(size_t)r * 64 + q]);
    float a0 = (float)sp.x, a1 = (float)sp.y;
    int ec = ecnt[r]; if (ec > ECAP) ec = ECAP;
    const int4* ep4 = (const int4*)(edges + (size_t)r * ECAP);
    for (int e = 0; e < ec; e += 4) {
        int4 ix = ep4[e >> 2];
        int j1 = (e + 1 < ec) ? ix.y : ix.x;
        int j2 = (e + 2 < ec) ? ix.z : ix.x;
        int j3 = (e + 3 < ec) ? ix.w : ix.x;
        uint_t u0 = Yu[(size_t)(base + ix.x) * 64 + q];
        uint_t u1 = Yu[(size_t)(base + j1) * 64 + q];
        uint_t u2 = Yu[(size_t)(base + j2) * 64 + q];
        uint_t u3 = Yu[(size_t)(base + j3) * 64 + q];
        f16x2 p0 = __builtin_bit_cast(f16x2, u0);
        a0 += (float)p0.x; a1 += (float)p0.y;
        if (e + 1 < ec) { f16x2 p = __builtin_bit_cast(f16x2, u1); a0 += (float)p.x; a1 += (float)p.y; }
        if (e + 2 < ec) { f16x2 p = __builtin_bit_cast(f16x2, u2); a0 += (float)p.x; a1 += (float)p.y; }
        if (e + 3 < ec) { f16x2 p = __builtin_bit_cast(f16x2, u3); a0 += (float)p.x; a1 += (float)p.y; }
    }
    float dv = dinv[r], mr = mf[r];
    f16x2 op;
    op.x = (f16)((dv * a0 + b2[2 * q]) * mr);
    op.y = (f16)((dv * a1 + b2[2 * q + 1]) * mr);
    ((uint_t*)ph)[(size_t)r * 64 + q] = __builtin_bit_cast(uint_t, op);
}

// ---- MFMA GEMM: [TM_ x 128] f16 @ [128 x Ntot] -> f16 ------------------
// mode=1 stores xg GATE-INTERLEAVED: slot (n&127)*4 + (n>>7).
#define ALD 136   // padded LDS leading dim in f16
__global__ __launch_bounds__(256) void kgemm_mfma(const f16* __restrict__ A,
        const float* __restrict__ Bw, int bTrans, int Ntot, int mode,
        const float* __restrict__ dinv, const float* __restrict__ ba,
        const float* __restrict__ bb, f16* __restrict__ Out) {
    __shared__ f16 As[64 * ALD];
    __shared__ f16 Bs[64 * ALD];
    int m0 = blockIdx.x * 64;
    int n0 = blockIdx.y * 64;
    int tid = threadIdx.x;
#pragma unroll
    for (int u = 0; u < 4; ++u) {
        int idx = u * 256 + tid;
        int row = idx >> 4, seg = idx & 15;
        *(f16x8*)&As[row * ALD + seg * 8] =
            *(const f16x8*)(A + (size_t)(m0 + row) * H_ + seg * 8);
    }
    if (bTrans) {   // Bw [Ntot][128]
#pragma unroll
        for (int u = 0; u < 16; ++u) {
            int idx = u * 256 + tid;
            int n = idx >> 6, k2 = (idx & 63) * 2;
            float2 v = *(const float2*)(Bw + (size_t)(n0 + n) * H_ + k2);
            f16x2 pk; pk.x = (f16)v.x; pk.y = (f16)v.y;
            *(uint_t*)&Bs[n * ALD + k2] = __builtin_bit_cast(uint_t, pk);
        }
    } else {        // Bw [128][Ntot]
#pragma unroll
        for (int u = 0; u < 16; ++u) {
            int idx = u * 256 + tid;
            int n = idx >> 6, k2 = (idx & 63) * 2;
            f16x2 pk;
            pk.x = (f16)Bw[(size_t)k2 * Ntot + n0 + n];
            pk.y = (f16)Bw[(size_t)(k2 + 1) * Ntot + n0 + n];
            *(uint_t*)&Bs[n * ALD + k2] = __builtin_bit_cast(uint_t, pk);
        }
    }
    __syncthreads();
    int w = tid >> 6, lane = tid & 63;
    int col = lane & 15, quad = lane >> 4;
    f32x4 acc[4] = {};
#pragma unroll
    for (int kk = 0; kk < 4; ++kk) {
        f16x8 af = *(const f16x8*)&As[(w * 16 + col) * ALD + kk * 32 + quad * 8];
#pragma unroll
        for (int nt = 0; nt < 4; ++nt) {
            f16x8 bf = *(const f16x8*)&Bs[(nt * 16 + col) * ALD + kk * 32 + quad * 8];
            acc[nt] = __builtin_amdgcn_mfma_f32_16x16x32_f16(af, bf, acc[nt], 0, 0, 0);
        }
    }
    if (mode == 0) {
        float dv[4];
#pragma unroll
        for (int reg = 0; reg < 4; ++reg)
            dv[reg] = dinv[m0 + w * 16 + quad * 4 + reg];
#pragma unroll
        for (int nt = 0; nt < 4; ++nt) {
            int n = n0 + nt * 16 + col;
#pragma unroll
            for (int reg = 0; reg < 4; ++reg) {
                int r = m0 + w * 16 + quad * 4 + reg;
                Out[(size_t)r * Ntot + n] = (f16)(dv[reg] * acc[nt][reg]);
            }
        }
    } else {
#pragma unroll
        for (int nt = 0; nt < 4; ++nt) {
            int n = n0 + nt * 16 + col;
            float bias = ba[n] + bb[n];
            int pos = (n & 127) * 4 + (n >> 7);   // gate-interleaved slot
#pragma unroll
            for (int reg = 0; reg < 4; ++reg) {
                int r = m0 + w * 16 + quad * 4 + reg;
                int t = r / M_, s = r % M_;
                Out[((size_t)s * T_ + t) * G_ + pos] = (f16)(acc[nt][reg] + bias);
            }
        }
    }
}

// ---- K7: 20 LSTM chains; MFMA matvec, weights as MFMA B-operands -------
// 8 waves; wave w owns h-indices [16w,16w+16). Per step each wave does
// 16 mfma_f32_16x16x32_f16 (4 gate types x 4 K-chunks). A = h broadcast
// (M=1: row 0 real, rows 1-15 finite garbage in unused C rows). Gates
// i,f,g,o for m = 16w+L land in lane L's acc[gt][0] -> in-register
// update, no gate LDS round-trip, no shuffles, ONE barrier/step.
__global__ __launch_bounds__(512, 2) void k7_lstm(const float* __restrict__ Whh,
        const f16* __restrict__ xg, f16* __restrict__ lo) {
    __shared__ ushort_t hb2[2][H_];   // double-buffered h (128 f16 each)
    int t = blockIdx.x, tid = threadIdx.x;
    int w = tid >> 6, lane = tid & 63;
    int col16 = lane & 15, quad = lane >> 4;
    int m = w * 16 + col16;
    // B fragments: wf[gt][kk] = W_hh[gt*128 + m][kk*32 + quad*8 + j], j=0..7
    f16x8 wf[4][4];
#pragma unroll
    for (int gt = 0; gt < 4; ++gt)
#pragma unroll
        for (int kk = 0; kk < 4; ++kk) {
            const float* wp = Whh + (size_t)(gt * H_ + m) * H_ + kk * 32 + quad * 8;
            float4 va = *(const float4*)wp;
            float4 vb = *(const float4*)(wp + 4);
            f16x8 f;
            f[0] = (f16)va.x; f[1] = (f16)va.y; f[2] = (f16)va.z; f[3] = (f16)va.w;
            f[4] = (f16)vb.x; f[5] = (f16)vb.y; f[6] = (f16)vb.z; f[7] = (f16)vb.w;
            wf[gt][kk] = f;
        }
    if (tid < H_) hb2[0][tid] = 0;
    float cst = 0.f;
    const f32x4 zero4 = {0.f, 0.f, 0.f, 0.f};
    const uint_t* xbase = (const uint_t*)xg;   // gate-interleaved, uint granularity
    uint2 xa[4], xb[4];
    if (quad == 0) {
#pragma unroll
        for (int k = 0; k < 4; ++k)
            xa[k] = *(const uint2*)(xbase + ((size_t)k * T_ + t) * 256 + m * 2);
    }
    __syncthreads();

#define LSTM_STEP(S, XV)                                                      \
    do {                                                                      \
        const ushort_t* hp = &hb2[(S) & 1][0];                                \
        uint4 u0 = *(const uint4*)(hp + quad * 8);                            \
        uint4 u1 = *(const uint4*)(hp + 32 + quad * 8);                       \
        uint4 u2 = *(const uint4*)(hp + 64 + quad * 8);                       \
        uint4 u3 = *(const uint4*)(hp + 96 + quad * 8);                       \
        f16x8 a0 = __builtin_bit_cast(f16x8, u0);                             \
        f16x8 a1 = __builtin_bit_cast(f16x8, u1);                             \
        f16x8 a2 = __builtin_bit_cast(f16x8, u2);                             \
        f16x8 a3 = __builtin_bit_cast(f16x8, u3);                             \
        f32x4 g0 = __builtin_amdgcn_mfma_f32_16x16x32_f16(a0, wf[0][0], zero4, 0, 0, 0); \
        f32x4 g1 = __builtin_amdgcn_mfma_f32_16x16x32_f16(a0, wf[1][0], zero4, 0, 0, 0); \
        f32x4 g2 = __builtin_amdgcn_mfma_f32_16x16x32_f16(a0, wf[2][0], zero4, 0, 0, 0); \
        f32x4 g3 = __builtin_amdgcn_mfma_f32_16x16x32_f16(a0, wf[3][0], zero4, 0, 0, 0); \
        g0 = __builtin_amdgcn_mfma_f32_16x16x32_f16(a1, wf[0][1], g0, 0, 0, 0); \
        g1 = __builtin_amdgcn_mfma_f32_16x16x32_f16(a1, wf[1][1], g1, 0, 0, 0); \
        g2 = __builtin_amdgcn_mfma_f32_16x16x32_f16(a1, wf[2][1], g2, 0, 0, 0); \
        g3 = __builtin_amdgcn_mfma_f32_16x16x32_f16(a1, wf[3][1], g3, 0, 0, 0); \
        g0 = __builtin_amdgcn_mfma_f32_16x16x32_f16(a2, wf[0][2], g0, 0, 0, 0); \
        g1 = __builtin_amdgcn_mfma_f32_16x16x32_f16(a2, wf[1][2], g1, 0, 0, 0); \
        g2 = __builtin_amdgcn_mfma_f32_16x16x32_f16(a2, wf[2][2], g2, 0, 0, 0); \
        g3 = __builtin_amdgcn_mfma_f32_16x16x32_f16(a2, wf[3][2], g3, 0, 0, 0); \
        g0 = __builtin_amdgcn_mfma_f32_16x16x32_f16(a3, wf[0][3], g0, 0, 0, 0); \
        g1 = __builtin_amdgcn_mfma_f32_16x16x32_f16(a3, wf[1][3], g1, 0, 0, 0); \
        g2 = __builtin_amdgcn_mfma_f32_16x16x32_f16(a3, wf[2][3], g2, 0, 0, 0); \
        g3 = __builtin_amdgcn_mfma_f32_16x16x32_f16(a3, wf[3][3], g3, 0, 0, 0); \
        if (quad == 0) {                                                      \
            f16x2 xlo = __builtin_bit_cast(f16x2, (XV).x);                    \
            f16x2 xhi = __builtin_bit_cast(f16x2, (XV).y);                    \
            float gi = fast_sig(g0[0] + (float)xlo.x);                        \
            float gf = fast_sig(g1[0] + (float)xlo.y);                        \
            float gg = fast_tanh(g2[0] + (float)xhi.x);                       \
            float go = fast_sig(g3[0] + (float)xhi.y);                        \
            cst = gf * cst + gi * gg;                                         \
            float hv_ = go * fast_tanh(cst);                                  \
            f16 hh = (f16)hv_;                                                \
            hb2[((S) & 1) ^ 1][m] = __builtin_bit_cast(ushort_t, hh);         \
            lo[((size_t)(S) * T_ + t) * H_ + m] = hh;                         \
        }                                                                     \
        BARRAW();                                                             \
    } while (0)

    for (int c2 = 0; c2 < 250; ++c2) {
        int s0 = c2 * 8;
        if (quad == 0) {
#pragma unroll
            for (int k = 0; k < 4; ++k)
                xb[k] = *(const uint2*)(xbase + ((size_t)(s0 + 4 + k) * T_ + t) * 256 + m * 2);
        }
#pragma unroll
        for (int k = 0; k < 4; ++k) LSTM_STEP(s0 + k, xa[k]);
        int nbs = (s0 + 8 <= M_ - 4) ? s0 + 8 : M_ - 4;
        if (quad == 0) {
#pragma unroll
            for (int k = 0; k < 4; ++k)
                xa[k] = *(const uint2*)(xbase + ((size_t)(nbs + k) * T_ + t) * 256 + m * 2);
        }
#pragma unroll
        for (int k = 0; k < 4; ++k) LSTM_STEP(s0 + 4 + k, xb[k]);
    }
#undef LSTM_STEP
}

// ---- K8: fc1(relu)+fc2; weights in VGPRs; stream 4 rows/iter -----------
__global__ __launch_bounds__(256) void k8_fc(const f16* __restrict__ lo,
        const float* __restrict__ w1, const float* __restrict__ fb1,
        const float* __restrict__ w2, const float* __restrict__ fb2,
        float* __restrict__ out) {
    __shared__ uint_t hl[4][H_ / 2];   // 4 rows x 128 f16
    __shared__ float o1f[4][H2_];
    int tid = threadIdx.x;
    int o = tid & 63, rr = tid >> 6;
    f16x2 w1c[64];
#pragma unroll
    for (int d = 0; d < 64; ++d) {
        f16x2 p;
        p.x = (f16)w1[(2 * d) * H2_ + o];
        p.y = (f16)w1[(2 * d + 1) * H2_ + o];
        w1c[d] = p;
    }
    int o2 = o & 31;
    float w2f[64];
#pragma unroll
    for (int d = 0; d < 64; ++d) w2f[d] = w2[d * OUT_ + o2];
    float fb1v = fb1[o], fb2v = fb2[o2];

    for (int r0 = blockIdx.x * 4; r0 < TM_; r0 += 512 * 4) {
        {
            int row = tid >> 6, qq = tid & 63;
            hl[row][qq] = ((const uint_t*)lo)[(size_t)(r0 + row) * 64 + qq];
        }
        __syncthreads();
        float acc = fb1v;
        const uint4* hb = (const uint4*)&hl[rr][0];
#pragma unroll
        for (int d = 0; d < 16; ++d) {
            uint4 hv = hb[d];
            acc = fdot2_(w1c[4 * d + 0], __builtin_bit_cast(f16x2, hv.x), acc);
            acc = fdot2_(w1c[4 * d + 1], __builtin_bit_cast(f16x2, hv.y), acc);
            acc = fdot2_(w1c[4 * d + 2], __builtin_bit_cast(f16x2, hv.z), acc);
            acc = fdot2_(w1c[4 * d + 3], __builtin_bit_cast(f16x2, hv.w), acc);
        }
        o1f[rr][o] = fmaxf(acc, 0.f);
        __syncthreads();
        if (o < OUT_) {
            float a2 = fb2v;
            const float4* ob = (const float4*)&o1f[rr][0];
#pragma unroll
            for (int d = 0; d < 16; ++d) {
                float4 v = ob[d];
                a2 += v.x * w2f[4 * d + 0] + v.y * w2f[4 * d + 1]
                    + v.z * w2f[4 * d + 2] + v.w * w2f[4 * d + 3];
            }
            out[(size_t)(r0 + rr) * OUT_ + o] = a2;
        }
        __syncthreads();
    }
}

extern "C" void kernel_launch(void* const* d_in, const int* in_sizes, int n_in,
                              void* d_out, int out_size, void* d_ws, size_t ws_size,
                              hipStream_t stream) {
    const float* positions = (const float*)d_in[0];
    const float* adjacency = (const float*)d_in[1];
    const void*  ego       = d_in[2];
    const float* W1   = (const float*)d_in[3];
    const float* b1   = (const float*)d_in[4];
    const float* W2   = (const float*)d_in[5];
    const float* b2   = (const float*)d_in[6];
    const float* W_ih = (const float*)d_in[7];
    const float* W_hh = (const float*)d_in[8];
    const float* b_ih = (const float*)d_in[9];
    const float* b_hh = (const float*)d_in[10];
    const float* fc1w = (const float*)d_in[11];
    const float* fc1b = (const float*)d_in[12];
    const float* fc2w = (const float*)d_in[13];
    const float* fc2b = (const float*)d_in[14];
    float* out = (float*)d_out;

    char* p = (char*)d_ws;
    auto alloc = [&](size_t bytes) {
        void* r = (void*)p;
        p += (bytes + 255) & ~(size_t)255;
        return r;
    };
    float* mf    = (float*)alloc((size_t)TM_ * 4);
    float* dinv  = (float*)alloc((size_t)TM_ * 4);
    int*   ecnt  = (int*)alloc((size_t)TM_ * 4);
    int*   edges = (int*)alloc((size_t)TM_ * ECAP * 4);   // aliased by lo later
    f16*   bufC  = (f16*)alloc((size_t)TM_ * H_ * 2);     // Y1, then Y2
    f16*   bufD  = (f16*)alloc((size_t)TM_ * H_ * 2);     // h1, then ph
    f16*   xg    = (f16*)alloc((size_t)TM_ * G_ * 2);
    f16*   Y1 = bufC, *Y2 = bufC;
    f16*   h1 = bufD, *ph = bufD;
    f16*   lo = (f16*)edges;    // edges dead after k5

    hipLaunchKernelGGL(k0_mask, dim3(40), dim3(1024), 0, stream, ego, mf, ecnt);
    hipLaunchKernelGGL(k1_scan, dim3(8, 20, 10), dim3(256), 0, stream,
                       adjacency, mf, ecnt, edges);
    hipLaunchKernelGGL(k2_y1, dim3(20000), dim3(256), 0, stream,
                       positions, W1, mf, ecnt, dinv, Y1);
    hipLaunchKernelGGL(k3_agg1, dim3(40000), dim3(64), 0, stream,
                       Y1, dinv, ecnt, edges, b1, h1);
    hipLaunchKernelGGL(kgemm_mfma, dim3(625, 2), dim3(256), 0, stream,
                       h1, W2, 0, 128, 0, dinv, (const float*)nullptr,
                       (const float*)nullptr, Y2);
    hipLaunchKernelGGL(k5_agg2, dim3(40000), dim3(64), 0, stream,
                       Y2, dinv, mf, ecnt, edges, b2, ph);
    hipLaunchKernelGGL(kgemm_mfma, dim3(625, 8), dim3(256), 0, stream,
                       ph, W_ih, 1, 512, 1, dinv, b_ih, b_hh, xg);
    hipLaunchKernelGGL(k7_lstm, dim3(20), dim3(512), 0, stream, W_hh, xg, lo);
    hipLaunchKernelGGL(k8_fc, dim3(512), dim3(256), 0, stream,
                       lo, fc1w, fc1b, fc2w, fc2b, out);
}

// Round 7
// 1653.548 us; speedup vs baseline: 1.1599x; 1.0137x over previous
//
#include <hip/hip_runtime.h>
#include <hip/hip_bf16.h>

#define T_   20
#define B_   4
#define NN_  500
#define M_   2000
#define TM_  40000   // T_*M_
#define H_   128
#define G_   512     // 4*H_
#define H2_  64
#define OUT_ 32
#define ECAP 64
#define TG_  (T_ * G_)

typedef unsigned short ushort_t;
typedef unsigned int   uint_t;
typedef _Float16       f16;
typedef f16 f16x2 __attribute__((ext_vector_type(2)));
typedef f16 f16x8 __attribute__((ext_vector_type(8)));
typedef float f32x4 __attribute__((ext_vector_type(4)));

#if defined(__has_builtin)
#  if __has_builtin(__builtin_amdgcn_fdot2)
#    define HAVE_FDOT2 1
#  endif
#endif

__device__ inline float fdot2_(f16x2 a, f16x2 b, float c) {
#ifdef HAVE_FDOT2
    return __builtin_amdgcn_fdot2(a, b, c, false);
#else
    return c + (float)a.x * (float)b.x + (float)a.y * (float)b.y;
#endif
}

__device__ inline float fast_sig(float x) {
    float e = __builtin_amdgcn_exp2f(x * -1.4426950408889634f);
    return __builtin_amdgcn_rcpf(1.f + e);
}
__device__ inline float fast_tanh(float x) {
    float e = __builtin_amdgcn_exp2f(x * 2.8853900817779268f);
    return 1.f - 2.f * __builtin_amdgcn_rcpf(e + 1.f);
}

// raw barrier: no compiler-inserted s_waitcnt vmcnt(0) drain.
// LDS pipe is in-order per CU (validated R3-R6: correct results).
#define BARRAW() asm volatile("s_barrier" ::: "memory")

// ---- K0: detect ego dtype + build mask[t][i] + zero ecnt ---------------
__global__ __launch_bounds__(1024) void k0_mask(const void* __restrict__ ego,
                                                float* __restrict__ mf,
                                                int* __restrict__ ecnt) {
    __shared__ int fl[3];
    int tid = threadIdx.x;
    if (tid < 3) fl[tid] = 0;
    __syncthreads();
    const uint_t* dw = (const uint_t*)ego;
    int a = 0, b = 0, c = 0;
    for (int i = tid; i < 2500; i += 1024) {   // 10 KB <= any dtype's size
        uint_t v = dw[i];
        bool isf32  = (v == 0x3F800000u);
        bool isbf16 = (v == 0x00003F80u) || (v == 0x3F803F80u);
        if (isf32)  a = 1;
        if (isbf16) b = 1;
        if (v > 1u && !isf32 && !isbf16) c = 1;
    }
    if (a) fl[0] = 1;
    if (b) fl[1] = 1;
    if (c) fl[2] = 1;
    __syncthreads();
    int mode;                       // 0=int32, 1=uint8, 2=f32, 3=bf16
    if (fl[1])      mode = 3;
    else if (fl[0]) mode = 2;
    else if (fl[2]) mode = 1;
    else            mode = 0;
    int e = blockIdx.x * 1024 + tid;
    if (e >= TM_) return;
    ecnt[e] = 0;
    int t = e / M_, i = e % M_;
    int bb = i / NN_, n = i % NN_;
    int src = (bb * T_ + t) * NN_ + n;
    bool on;
    if (mode == 0)      on = ((const int*)ego)[src] != 0;
    else if (mode == 1) on = ((const unsigned char*)ego)[src] != 0;
    else if (mode == 2) on = ((const float*)ego)[src] != 0.f;
    else                on = ((const ushort_t*)ego)[src] != 0;
    mf[e] = on ? 1.f : 0.f;
}

// ---- K1: strip-parallel adjacency scan, atomic slot alloc --------------
#define JSTRIP 200
__global__ void k1_scan(const float* __restrict__ adj, const float* __restrict__ mf,
                        int* __restrict__ ecnt, int* __restrict__ edges) {
    __shared__ float ms[JSTRIP];
    int t = blockIdx.y, j0 = blockIdx.z * JSTRIP;
    int i = blockIdx.x * 256 + threadIdx.x;
    for (int idx = threadIdx.x; idx < JSTRIP; idx += 256)
        ms[idx] = mf[t * M_ + j0 + idx];
    __syncthreads();
    if (i >= M_) return;
    if (mf[t * M_ + i] == 0.f) return;          // masked column: no edges
    const float* ap = adj + (size_t)t * M_ * M_ + (size_t)j0 * M_ + i;
    int r = t * M_ + i;
    int* ep = edges + (size_t)r * ECAP;
#pragma unroll 8
    for (int jj = 0; jj < JSTRIP; ++jj) {
        float av = ap[(size_t)jj * M_];
        if (av != 0.f && ms[jj] != 0.f) {
            int pos = atomicAdd(&ecnt[r], 1);
            if (pos < ECAP) ep[pos] = j0 + jj;
        }
    }
}

// ---- K2: dinv from ecnt/mf; Y1 = dinv * (x @ W1) -----------------------
__global__ void k2_y1(const float* __restrict__ pos, const float* __restrict__ W1,
                      const float* __restrict__ mf, const int* __restrict__ ecnt,
                      float* __restrict__ dinv, f16* __restrict__ Y1) {
    int gid = blockIdx.x * 256 + threadIdx.x;    // over TM_*H_
    int r = gid >> 7, h = gid & 127;
    if (r >= TM_) return;
    float mr = mf[r];
    int cnt = ecnt[r];
    float dv = (mr != 0.f) ? __frsqrt_rn((float)(cnt + 1)) : 0.f;
    if (h == 0) dinv[r] = dv;
    float2 xy = ((const float2*)pos)[r];
    float v = xy.x * W1[h] + xy.y * W1[H_ + h];
    Y1[gid] = (f16)(dv * v);
}

// ---- K3: h1 = relu(dinv*(sum_edges Y1 + Y1_self) + b1), f16x2 lanes ----
__global__ __launch_bounds__(64) void k3_agg1(const f16* __restrict__ Y1,
        const float* __restrict__ dinv, const int* __restrict__ ecnt,
        const int* __restrict__ edges, const float* __restrict__ b1,
        f16* __restrict__ h1) {
    int r = blockIdx.x, q = threadIdx.x;   // q: h-pair index 0..63
    int t = r / M_, base = t * M_;
    const uint_t* Yu = (const uint_t*)Y1;
    f16x2 sp = __builtin_bit_cast(f16x2, Yu[(size_t)r * 64 + q]);
    float a0 = (float)sp.x, a1 = (float)sp.y;
    int ec = ecnt[r]; if (ec > ECAP) ec = ECAP;
    const int4* ep4 = (const int4*)(edges + (size_t)r * ECAP);
    for (int e = 0; e < ec; e += 4) {
        int4 ix = ep4[e >> 2];
        int j1 = (e + 1 < ec) ? ix.y : ix.x;
        int j2 = (e + 2 < ec) ? ix.z : ix.x;
        int j3 = (e + 3 < ec) ? ix.w : ix.x;
        uint_t u0 = Yu[(size_t)(base + ix.x) * 64 + q];
        uint_t u1 = Yu[(size_t)(base + j1) * 64 + q];
        uint_t u2 = Yu[(size_t)(base + j2) * 64 + q];
        uint_t u3 = Yu[(size_t)(base + j3) * 64 + q];
        f16x2 p0 = __builtin_bit_cast(f16x2, u0);
        a0 += (float)p0.x; a1 += (float)p0.y;
        if (e + 1 < ec) { f16x2 p = __builtin_bit_cast(f16x2, u1); a0 += (float)p.x; a1 += (float)p.y; }
        if (e + 2 < ec) { f16x2 p = __builtin_bit_cast(f16x2, u2); a0 += (float)p.x; a1 += (float)p.y; }
        if (e + 3 < ec) { f16x2 p = __builtin_bit_cast(f16x2, u3); a0 += (float)p.x; a1 += (float)p.y; }
    }
    float dv = dinv[r];
    float o0 = dv * a0 + b1[2 * q];
    float o1 = dv * a1 + b1[2 * q + 1];
    f16x2 op; op.x = (f16)fmaxf(o0, 0.f); op.y = (f16)fmaxf(o1, 0.f);
    ((uint_t*)h1)[(size_t)r * 64 + q] = __builtin_bit_cast(uint_t, op);
}

// ---- K5: placeholder = (dinv*(sum Y2 + Y2_self) + b2) * m --------------
__global__ __launch_bounds__(64) void k5_agg2(const f16* __restrict__ Y2,
        const float* __restrict__ dinv, const float* __restrict__ mf,
        const int* __restrict__ ecnt, const int* __restrict__ edges,
        const float* __restrict__ b2, f16* __restrict__ ph) {
    int r = blockIdx.x, q = threadIdx.x;
    int t = r / M_, base = t * M_;
    const uint_t* Yu = (const uint_t*)Y2;
    f16x2 sp = __builtin_bit_cast(f16x2, Yu[(size_t)r * 64 + q]);
    float a0 = (float)sp.x, a1 = (float)sp.y;
    int ec = ecnt[r]; if (ec > ECAP) ec = ECAP;
    const int4* ep4 = (const int4*)(edges + (size_t)r * ECAP);
    for (int e = 0; e < ec; e += 4) {
        int4 ix = ep4[e >> 2];
        int j1 = (e + 1 < ec) ? ix.y : ix.x;
        int j2 = (e + 2 < ec) ? ix.z : ix.x;
        int j3 = (e + 3 < ec) ? ix.w : ix.x;
        uint_t u0 = Yu[(size_t)(base + ix.x) * 64 + q];
        uint_t u1 = Yu[(size_t)(base + j1) * 64 + q];
        uint_t u2 = Yu[(size_t)(base + j2) * 64 + q];
        uint_t u3 = Yu[(size_t)(base + j3) * 64 + q];
        f16x2 p0 = __builtin_bit_cast(f16x2, u0);
        a0 += (float)p0.x; a1 += (float)p0.y;
        if (e + 1 < ec) { f16x2 p = __builtin_bit_cast(f16x2, u1); a0 += (float)p.x; a1 += (float)p.y; }
        if (e + 2 < ec) { f16x2 p = __builtin_bit_cast(f16x2, u2); a0 += (float)p.x; a1 += (float)p.y; }
        if (e + 3 < ec) { f16x2 p = __builtin_bit_cast(f16x2, u3); a0 += (float)p.x; a1 += (float)p.y; }
    }
    float dv = dinv[r], mr = mf[r];
    f16x2 op;
    op.x = (f16)((dv * a0 + b2[2 * q]) * mr);
    op.y = (f16)((dv * a1 + b2[2 * q + 1]) * mr);
    ((uint_t*)ph)[(size_t)r * 64 + q] = __builtin_bit_cast(uint_t, op);
}

// ---- MFMA GEMM: [TM_ x 128] f16 @ [128 x Ntot] -> f16 ------------------
// mode=1 stores xg GATE-INTERLEAVED: slot (n&127)*4 + (n>>7).
#define ALD 136   // padded LDS leading dim in f16
__global__ __launch_bounds__(256) void kgemm_mfma(const f16* __restrict__ A,
        const float* __restrict__ Bw, int bTrans, int Ntot, int mode,
        const float* __restrict__ dinv, const float* __restrict__ ba,
        const float* __restrict__ bb, f16* __restrict__ Out) {
    __shared__ f16 As[64 * ALD];
    __shared__ f16 Bs[64 * ALD];
    int m0 = blockIdx.x * 64;
    int n0 = blockIdx.y * 64;
    int tid = threadIdx.x;
#pragma unroll
    for (int u = 0; u < 4; ++u) {
        int idx = u * 256 + tid;
        int row = idx >> 4, seg = idx & 15;
        *(f16x8*)&As[row * ALD + seg * 8] =
            *(const f16x8*)(A + (size_t)(m0 + row) * H_ + seg * 8);
    }
    if (bTrans) {   // Bw [Ntot][128]
#pragma unroll
        for (int u = 0; u < 16; ++u) {
            int idx = u * 256 + tid;
            int n = idx >> 6, k2 = (idx & 63) * 2;
            float2 v = *(const float2*)(Bw + (size_t)(n0 + n) * H_ + k2);
            f16x2 pk; pk.x = (f16)v.x; pk.y = (f16)v.y;
            *(uint_t*)&Bs[n * ALD + k2] = __builtin_bit_cast(uint_t, pk);
        }
    } else {        // Bw [128][Ntot]
#pragma unroll
        for (int u = 0; u < 16; ++u) {
            int idx = u * 256 + tid;
            int n = idx >> 6, k2 = (idx & 63) * 2;
            f16x2 pk;
            pk.x = (f16)Bw[(size_t)k2 * Ntot + n0 + n];
            pk.y = (f16)Bw[(size_t)(k2 + 1) * Ntot + n0 + n];
            *(uint_t*)&Bs[n * ALD + k2] = __builtin_bit_cast(uint_t, pk);
        }
    }
    __syncthreads();
    int w = tid >> 6, lane = tid & 63;
    int col = lane & 15, quad = lane >> 4;
    f32x4 acc[4] = {};
#pragma unroll
    for (int kk = 0; kk < 4; ++kk) {
        f16x8 af = *(const f16x8*)&As[(w * 16 + col) * ALD + kk * 32 + quad * 8];
#pragma unroll
        for (int nt = 0; nt < 4; ++nt) {
            f16x8 bf = *(const f16x8*)&Bs[(nt * 16 + col) * ALD + kk * 32 + quad * 8];
            acc[nt] = __builtin_amdgcn_mfma_f32_16x16x32_f16(af, bf, acc[nt], 0, 0, 0);
        }
    }
    if (mode == 0) {
        float dv[4];
#pragma unroll
        for (int reg = 0; reg < 4; ++reg)
            dv[reg] = dinv[m0 + w * 16 + quad * 4 + reg];
#pragma unroll
        for (int nt = 0; nt < 4; ++nt) {
            int n = n0 + nt * 16 + col;
#pragma unroll
            for (int reg = 0; reg < 4; ++reg) {
                int r = m0 + w * 16 + quad * 4 + reg;
                Out[(size_t)r * Ntot + n] = (f16)(dv[reg] * acc[nt][reg]);
            }
        }
    } else {
#pragma unroll
        for (int nt = 0; nt < 4; ++nt) {
            int n = n0 + nt * 16 + col;
            float bias = ba[n] + bb[n];
            int pos = (n & 127) * 4 + (n >> 7);   // gate-interleaved slot
#pragma unroll
            for (int reg = 0; reg < 4; ++reg) {
                int r = m0 + w * 16 + quad * 4 + reg;
                int t = r / M_, s = r % M_;
                Out[((size_t)s * T_ + t) * G_ + pos] = (f16)(acc[nt][reg] + bias);
            }
        }
    }
}

// ---- K7: 20 LSTM chains; 4 waves (1/SIMD), MFMA matvec -----------------
// Wave w owns h-outs [32w, 32w+32) = 2 col-groups (hb) x 4 gates = 8 accs,
// 32 MFMA/step. A = h broadcast (all 16 M-rows identical -> any row/quad
// holds the result). Update split across quads 0/1 (hb = quad), 1 state
// per active lane: 10 trans-ops/step. 16 ds_read_b128 per CU per step
// (vs 32 at 8 waves) — LDS-pipe serialization was the R6 floor.
__global__ __launch_bounds__(256, 1) void k7_lstm(const float* __restrict__ Whh,
        const f16* __restrict__ xg, f16* __restrict__ lo) {
    __shared__ ushort_t hb2[2][H_];   // double-buffered h (128 f16 each)
    int t = blockIdx.x, tid = threadIdx.x;
    int w = tid >> 6, lane = tid & 63;
    int col16 = lane & 15, quad = lane >> 4;
    // B fragments: wf[hb][gt][kk] = W_hh[gt*128 + (32w + hb*16 + col16)][kk*32+quad*8+j]
    f16x8 wf[2][4][4];
#pragma unroll
    for (int hb = 0; hb < 2; ++hb)
#pragma unroll
        for (int gt = 0; gt < 4; ++gt)
#pragma unroll
            for (int kk = 0; kk < 4; ++kk) {
                const float* wp = Whh
                    + (size_t)(gt * H_ + w * 32 + hb * 16 + col16) * H_
                    + kk * 32 + quad * 8;
                float4 va = *(const float4*)wp;
                float4 vb = *(const float4*)(wp + 4);
                f16x8 f;
                f[0] = (f16)va.x; f[1] = (f16)va.y; f[2] = (f16)va.z; f[3] = (f16)va.w;
                f[4] = (f16)vb.x; f[5] = (f16)vb.y; f[6] = (f16)vb.z; f[7] = (f16)vb.w;
                wf[hb][gt][kk] = f;
            }
    if (tid < H_) hb2[0][tid] = 0;
    else          hb2[1][tid - H_] = 0;
    bool upd = (quad < 2);
    int midx = w * 32 + quad * 16 + col16;   // valid for quad 0/1
    float cst = 0.f;
    const f32x4 zero4 = {0.f, 0.f, 0.f, 0.f};
    const uint_t* xbase = (const uint_t*)xg;   // gate-interleaved, uint granularity
    uint2 xa[4], xb[4];
    if (upd) {
#pragma unroll
        for (int k = 0; k < 4; ++k)
            xa[k] = *(const uint2*)(xbase + ((size_t)k * T_ + t) * 256 + midx * 2);
    }
    __syncthreads();

#define LSTM_STEP(S, XV)                                                      \
    do {                                                                      \
        const ushort_t* hp = &hb2[(S) & 1][0];                                \
        uint4 u0 = *(const uint4*)(hp + quad * 8);                            \
        uint4 u1 = *(const uint4*)(hp + 32 + quad * 8);                       \
        uint4 u2 = *(const uint4*)(hp + 64 + quad * 8);                       \
        uint4 u3 = *(const uint4*)(hp + 96 + quad * 8);                       \
        f16x8 a0 = __builtin_bit_cast(f16x8, u0);                             \
        f16x8 a1 = __builtin_bit_cast(f16x8, u1);                             \
        f16x8 a2 = __builtin_bit_cast(f16x8, u2);                             \
        f16x8 a3 = __builtin_bit_cast(f16x8, u3);                             \
        f32x4 acc[2][4];                                                      \
        _Pragma("unroll")                                                     \
        for (int hb = 0; hb < 2; ++hb) {                                      \
            _Pragma("unroll")                                                 \
            for (int gt = 0; gt < 4; ++gt) {                                  \
                f32x4 g;                                                      \
                g = __builtin_amdgcn_mfma_f32_16x16x32_f16(a0, wf[hb][gt][0], zero4, 0, 0, 0); \
                g = __builtin_amdgcn_mfma_f32_16x16x32_f16(a1, wf[hb][gt][1], g, 0, 0, 0);     \
                g = __builtin_amdgcn_mfma_f32_16x16x32_f16(a2, wf[hb][gt][2], g, 0, 0, 0);     \
                g = __builtin_amdgcn_mfma_f32_16x16x32_f16(a3, wf[hb][gt][3], g, 0, 0, 0);     \
                acc[hb][gt] = g;                                              \
            }                                                                 \
        }                                                                     \
        if (upd) {                                                            \
            float v0 = quad ? acc[1][0][0] : acc[0][0][0];                    \
            float v1 = quad ? acc[1][1][0] : acc[0][1][0];                    \
            float v2 = quad ? acc[1][2][0] : acc[0][2][0];                    \
            float v3 = quad ? acc[1][3][0] : acc[0][3][0];                    \
            f16x2 xlo = __builtin_bit_cast(f16x2, (XV).x);                    \
            f16x2 xhi = __builtin_bit_cast(f16x2, (XV).y);                    \
            float gi = fast_sig(v0 + (float)xlo.x);                           \
            float gf = fast_sig(v1 + (float)xlo.y);                           \
            float gg = fast_tanh(v2 + (float)xhi.x);                          \
            float go = fast_sig(v3 + (float)xhi.y);                           \
            cst = gf * cst + gi * gg;                                         \
            float hv_ = go * fast_tanh(cst);                                  \
            f16 hh = (f16)hv_;                                                \
            hb2[((S) & 1) ^ 1][midx] = __builtin_bit_cast(ushort_t, hh);      \
            lo[((size_t)(S) * T_ + t) * H_ + midx] = hh;                      \
        }                                                                     \
        BARRAW();                                                             \
    } while (0)

    for (int c2 = 0; c2 < 250; ++c2) {
        int s0 = c2 * 8;
        if (upd) {
#pragma unroll
            for (int k = 0; k < 4; ++k)
                xb[k] = *(const uint2*)(xbase + ((size_t)(s0 + 4 + k) * T_ + t) * 256 + midx * 2);
        }
#pragma unroll
        for (int k = 0; k < 4; ++k) LSTM_STEP(s0 + k, xa[k]);
        int nbs = (s0 + 8 <= M_ - 4) ? s0 + 8 : M_ - 4;
        if (upd) {
#pragma unroll
            for (int k = 0; k < 4; ++k)
                xa[k] = *(const uint2*)(xbase + ((size_t)(nbs + k) * T_ + t) * 256 + midx * 2);
        }
#pragma unroll
        for (int k = 0; k < 4; ++k) LSTM_STEP(s0 + 4 + k, xb[k]);
    }
#undef LSTM_STEP
}

// ---- K8: fc1(relu)+fc2; weights in VGPRs; stream 4 rows/iter -----------
__global__ __launch_bounds__(256) void k8_fc(const f16* __restrict__ lo,
        const float* __restrict__ w1, const float* __restrict__ fb1,
        const float* __restrict__ w2, const float* __restrict__ fb2,
        float* __restrict__ out) {
    __shared__ uint_t hl[4][H_ / 2];   // 4 rows x 128 f16
    __shared__ float o1f[4][H2_];
    int tid = threadIdx.x;
    int o = tid & 63, rr = tid >> 6;
    f16x2 w1c[64];
#pragma unroll
    for (int d = 0; d < 64; ++d) {
        f16x2 p;
        p.x = (f16)w1[(2 * d) * H2_ + o];
        p.y = (f16)w1[(2 * d + 1) * H2_ + o];
        w1c[d] = p;
    }
    int o2 = o & 31;
    float w2f[64];
#pragma unroll
    for (int d = 0; d < 64; ++d) w2f[d] = w2[d * OUT_ + o2];
    float fb1v = fb1[o], fb2v = fb2[o2];

    for (int r0 = blockIdx.x * 4; r0 < TM_; r0 += 512 * 4) {
        {
            int row = tid >> 6, qq = tid & 63;
            hl[row][qq] = ((const uint_t*)lo)[(size_t)(r0 + row) * 64 + qq];
        }
        __syncthreads();
        float acc = fb1v;
        const uint4* hb = (const uint4*)&hl[rr][0];
#pragma unroll
        for (int d = 0; d < 16; ++d) {
            uint4 hv = hb[d];
            acc = fdot2_(w1c[4 * d + 0], __builtin_bit_cast(f16x2, hv.x), acc);
            acc = fdot2_(w1c[4 * d + 1], __builtin_bit_cast(f16x2, hv.y), acc);
            acc = fdot2_(w1c[4 * d + 2], __builtin_bit_cast(f16x2, hv.z), acc);
            acc = fdot2_(w1c[4 * d + 3], __builtin_bit_cast(f16x2, hv.w), acc);
        }
        o1f[rr][o] = fmaxf(acc, 0.f);
        __syncthreads();
        if (o < OUT_) {
            float a2 = fb2v;
            const float4* ob = (const float4*)&o1f[rr][0];
#pragma unroll
            for (int d = 0; d < 16; ++d) {
                float4 v = ob[d];
                a2 += v.x * w2f[4 * d + 0] + v.y * w2f[4 * d + 1]
                    + v.z * w2f[4 * d + 2] + v.w * w2f[4 * d + 3];
            }
            out[(size_t)(r0 + rr) * OUT_ + o] = a2;
        }
        __syncthreads();
    }
}

extern "C" void kernel_launch(void* const* d_in, const int* in_sizes, int n_in,
                              void* d_out, int out_size, void* d_ws, size_t ws_size,
                              hipStream_t stream) {
    const float* positions = (const float*)d_in[0];
    const float* adjacency = (const float*)d_in[1];
    const void*  ego       = d_in[2];
    const float* W1   = (const float*)d_in[3];
    const float* b1   = (const float*)d_in[4];
    const float* W2   = (const float*)d_in[5];
    const float* b2   = (const float*)d_in[6];
    const float* W_ih = (const float*)d_in[7];
    const float* W_hh = (const float*)d_in[8];
    const float* b_ih = (const float*)d_in[9];
    const float* b_hh = (const float*)d_in[10];
    const float* fc1w = (const float*)d_in[11];
    const float* fc1b = (const float*)d_in[12];
    const float* fc2w = (const float*)d_in[13];
    const float* fc2b = (const float*)d_in[14];
    float* out = (float*)d_out;

    char* p = (char*)d_ws;
    auto alloc = [&](size_t bytes) {
        void* r = (void*)p;
        p += (bytes + 255) & ~(size_t)255;
        return r;
    };
    float* mf    = (float*)alloc((size_t)TM_ * 4);
    float* dinv  = (float*)alloc((size_t)TM_ * 4);
    int*   ecnt  = (int*)alloc((size_t)TM_ * 4);
    int*   edges = (int*)alloc((size_t)TM_ * ECAP * 4);   // aliased by lo later
    f16*   bufC  = (f16*)alloc((size_t)TM_ * H_ * 2);     // Y1, then Y2
    f16*   bufD  = (f16*)alloc((size_t)TM_ * H_ * 2);     // h1, then ph
    f16*   xg    = (f16*)alloc((size_t)TM_ * G_ * 2);
    f16*   Y1 = bufC, *Y2 = bufC;
    f16*   h1 = bufD, *ph = bufD;
    f16*   lo = (f16*)edges;    // edges dead after k5

    hipLaunchKernelGGL(k0_mask, dim3(40), dim3(1024), 0, stream, ego, mf, ecnt);
    hipLaunchKernelGGL(k1_scan, dim3(8, 20, 10), dim3(256), 0, stream,
                       adjacency, mf, ecnt, edges);
    hipLaunchKernelGGL(k2_y1, dim3(20000), dim3(256), 0, stream,
                       positions, W1, mf, ecnt, dinv, Y1);
    hipLaunchKernelGGL(k3_agg1, dim3(40000), dim3(64), 0, stream,
                       Y1, dinv, ecnt, edges, b1, h1);
    hipLaunchKernelGGL(kgemm_mfma, dim3(625, 2), dim3(256), 0, stream,
                       h1, W2, 0, 128, 0, dinv, (const float*)nullptr,
                       (const float*)nullptr, Y2);
    hipLaunchKernelGGL(k5_agg2, dim3(40000), dim3(64), 0, stream,
                       Y2, dinv, mf, ecnt, edges, b2, ph);
    hipLaunchKernelGGL(kgemm_mfma, dim3(625, 8), dim3(256), 0, stream,
                       ph, W_ih, 1, 512, 1, dinv, b_ih, b_hh, xg);
    hipLaunchKernelGGL(k7_lstm, dim3(20), dim3(256), 0, stream, W_hh, xg, lo);
    hipLaunchKernelGGL(k8_fc, dim3(512), dim3(256), 0, stream,
                       lo, fc1w, fc1b, fc2w, fc2b, out);
}